// Round 1
// baseline (411.879 us; speedup 1.0000x reference)
//
#include <hip/hip_runtime.h>

// MSMultiHeadAttentionBlock: spiking linear attention block on MI355X (gfx950)
// B=4, N=4096, C=1024, H=16, D=64. All I/O f32.
// Pipeline: quant -> conv_bn(GEMM)+quant for q/k/v -> scores=K^T V (exact ints)
//           -> out=Q*scores*0.125 -> quant -> conv_bn(GEMM) -> f32 out.

typedef __attribute__((ext_vector_type(8))) short bf16x8;
typedef __attribute__((ext_vector_type(4))) float f32x4;
typedef __attribute__((ext_vector_type(4))) unsigned short us4;
typedef unsigned short u16;
typedef unsigned int u32;

__device__ __forceinline__ u16 rne_bf16(float f) {
  u32 u = __float_as_uint(f);
  u += 0x7FFFu + ((u >> 16) & 1u);
  return (u16)(u >> 16);
}
__device__ __forceinline__ float bf16f(u16 h) { return __uint_as_float(((u32)h) << 16); }
// quant_spike forward: round-half-even(clamp(x,0,4)) — rintf is RNE, matches jnp.round
__device__ __forceinline__ float spikef(float v) { return rintf(fminf(fmaxf(v, 0.f), 4.f)); }

__device__ __forceinline__ void g2l16(const void* g, void* l) {
  // async global->LDS, 16B per lane; LDS dest = wave-uniform base + lane*16
  __builtin_amdgcn_global_load_lds((const __attribute__((address_space(1))) void*)g,
                                   (__attribute__((address_space(3))) void*)l, 16, 0, 0);
}

__device__ __forceinline__ f32x4 mfma16(bf16x8 a, bf16x8 b, f32x4 c) {
  return __builtin_amdgcn_mfma_f32_16x16x32_bf16(a, b, c, 0, 0, 0);
}

// ---------------- elementwise prep kernels ----------------

// spike(x) -> bf16, vectorized x4
__global__ __launch_bounds__(256) void quant_k(const float4* __restrict__ in,
                                               us4* __restrict__ out, int n4) {
  int i = blockIdx.x * 256 + threadIdx.x;
  if (i >= n4) return;
  float4 v = in[i];
  us4 o;
  o[0] = rne_bf16(spikef(v.x));
  o[1] = rne_bf16(spikef(v.y));
  o[2] = rne_bf16(spikef(v.z));
  o[3] = rne_bf16(spikef(v.w));
  out[i] = o;
}

// w f32 -> (hi bf16, lo bf16) split for ~f32-precision MFMA
__global__ __launch_bounds__(256) void wsplit_k(const float4* __restrict__ w,
                                                us4* __restrict__ hi, us4* __restrict__ lo,
                                                int n4) {
  int i = blockIdx.x * 256 + threadIdx.x;
  if (i >= n4) return;
  float4 v = w[i];
  float c[4] = {v.x, v.y, v.z, v.w};
  us4 h, l;
#pragma unroll
  for (int j = 0; j < 4; ++j) {
    u16 hb = rne_bf16(c[j]);
    h[j] = hb;
    l[j] = rne_bf16(c[j] - bf16f(hb));
  }
  hi[i] = h;
  lo[i] = l;
}

// beta = b*s + t (per-channel fused affine)
__global__ __launch_bounds__(256) void beta_k(const float* __restrict__ b,
                                              const float* __restrict__ s,
                                              const float* __restrict__ t,
                                              float* __restrict__ beta) {
  int i = blockIdx.x * 256 + threadIdx.x;
  if (i < 1024) beta[i] = b[i] * s[i] + t[i];
}

// ---------------- main GEMM: C(16384x1024) = A(bf16) x W^T, fused epilogue ----------------
// MODE 0: spike -> bf16, natural (B,N,C) layout        (Q path)
// MODE 1: spike -> bf16, transposed (B,H,D,N) layout   (K/V paths)
// MODE 2: f32, natural layout, no spike                (O path -> d_out)
// SPLIT: accumulate A*Bhi + A*Blo (split-bf16 weights)
template <int MODE, bool SPLIT>
__global__ __launch_bounds__(256) void gemm_k(const u16* __restrict__ A,
                                              const u16* __restrict__ Bh,
                                              const u16* __restrict__ Bl,
                                              const float* __restrict__ alpha,
                                              const float* __restrict__ beta,
                                              void* __restrict__ outp) {
  constexpr int K = 1024;
  __shared__ u16 lsA[128 * 32];
  __shared__ u16 lsBh[128 * 32];
  __shared__ u16 lsBl[SPLIT ? 128 * 32 : 8];

  const int t = threadIdx.x;
  const int bm = blockIdx.x, bn = blockIdx.y;
  const int wv = t >> 6, ln = t & 63;
  const int wm = wv >> 1, wn = wv & 1;
  const int lr = ln & 15, lk = (ln >> 4) << 3, lg = ln >> 4;

  f32x4 acc[4][4] = {};

  const int srow = t >> 2;        // 0..63
  const int scol = (t & 3) << 3;  // 0,8,16,24
  const size_t abase = (size_t)(bm * 128) * K;
  const size_t bbase = (size_t)(bn * 128) * K;

  for (int kt = 0; kt < K / 32; ++kt) {
    __syncthreads();  // previous tile fully consumed
    const int k0 = kt * 32 + scol;
#pragma unroll
    for (int i = 0; i < 2; ++i) {
      g2l16(A + abase + (size_t)(i * 64 + srow) * K + k0, lsA + i * 2048 + wv * 512);
      g2l16(Bh + bbase + (size_t)(i * 64 + srow) * K + k0, lsBh + i * 2048 + wv * 512);
      if constexpr (SPLIT)
        g2l16(Bl + bbase + (size_t)(i * 64 + srow) * K + k0, lsBl + i * 2048 + wv * 512);
    }
    __syncthreads();  // drains vmcnt (global_load_lds) per barrier semantics

    bf16x8 af[4], bfh[4], bfl[4];
#pragma unroll
    for (int mi = 0; mi < 4; ++mi)
      af[mi] = *(const bf16x8*)&lsA[(wm * 64 + mi * 16 + lr) * 32 + lk];
#pragma unroll
    for (int nj = 0; nj < 4; ++nj) {
      bfh[nj] = *(const bf16x8*)&lsBh[(wn * 64 + nj * 16 + lr) * 32 + lk];
      if constexpr (SPLIT)
        bfl[nj] = *(const bf16x8*)&lsBl[(wn * 64 + nj * 16 + lr) * 32 + lk];
    }
#pragma unroll
    for (int mi = 0; mi < 4; ++mi)
#pragma unroll
      for (int nj = 0; nj < 4; ++nj) {
        acc[mi][nj] = mfma16(af[mi], bfh[nj], acc[mi][nj]);
        if constexpr (SPLIT) acc[mi][nj] = mfma16(af[mi], bfl[nj], acc[mi][nj]);
      }
  }

  // epilogue: val = acc*alpha[n] + beta[n]  (alpha = s, beta = b*s+t)
#pragma unroll
  for (int nj = 0; nj < 4; ++nj) {
    const int gn = bn * 128 + wn * 64 + nj * 16 + lr;
    const float al = alpha[gn], be = beta[gn];
#pragma unroll
    for (int mi = 0; mi < 4; ++mi) {
      const int gm0 = bm * 128 + wm * 64 + mi * 16 + lg * 4;
      if constexpr (MODE == 0) {
        u16* o = (u16*)outp;
#pragma unroll
        for (int r = 0; r < 4; ++r) {
          float v = spikef(acc[mi][nj][r] * al + be);
          o[(size_t)(gm0 + r) * 1024 + gn] = rne_bf16(v);
        }
      } else if constexpr (MODE == 1) {
        // transposed store: dst[((b*16+h)*64+d)*4096 + tok], 4 consecutive tokens -> 8B
        u16* o = (u16*)outp;
        const int bi = gm0 >> 12, tok = gm0 & 4095;
        const int hh = gn >> 6, dd = gn & 63;
        us4 pack;
#pragma unroll
        for (int r = 0; r < 4; ++r)
          pack[r] = rne_bf16(spikef(acc[mi][nj][r] * al + be));
        *(us4*)&o[((size_t)(bi * 16 + hh) * 64 + dd) * 4096 + tok] = pack;
      } else {
        float* o = (float*)outp;
#pragma unroll
        for (int r = 0; r < 4; ++r)
          o[(size_t)(gm0 + r) * 1024 + gn] = acc[mi][nj][r] * al + be;
      }
    }
  }
}

// ---------------- scores = K^T V per (b,h): 64x64, K-dim 4096 split into 4 chunks ----------------
// Kt/Vt are (B*H, 64, 4096) bf16 (k-contiguous). Exact integer accumulation; atomicAdd
// of integers < 2^24 is order-independent -> deterministic.
__global__ __launch_bounds__(256) void scores_k(const u16* __restrict__ Kt,
                                                const u16* __restrict__ Vt,
                                                float* __restrict__ sc) {
  __shared__ u16 lsA[64 * 64], lsB[64 * 64];
  const int t = threadIdx.x;
  const int bh = blockIdx.y, ck = blockIdx.x;
  const int wv = t >> 6, ln = t & 63;
  const int wm = wv & 1, wn = wv >> 1;
  const int lr = ln & 15, lk = (ln >> 4) << 3, lg = ln >> 4;
  const size_t base = (size_t)bh * 64 * 4096 + (size_t)ck * 1024;
  f32x4 acc[2][2] = {};
  const int srow = t >> 3;        // 0..31
  const int scol = (t & 7) << 3;  // 0..56

  for (int kt = 0; kt < 16; ++kt) {
    __syncthreads();
#pragma unroll
    for (int i = 0; i < 2; ++i) {
      g2l16(Kt + base + (size_t)(i * 32 + srow) * 4096 + kt * 64 + scol,
            lsA + i * 2048 + wv * 512);
      g2l16(Vt + base + (size_t)(i * 32 + srow) * 4096 + kt * 64 + scol,
            lsB + i * 2048 + wv * 512);
    }
    __syncthreads();
#pragma unroll
    for (int ks = 0; ks < 2; ++ks) {
      bf16x8 fa[2], fb[2];
#pragma unroll
      for (int mi = 0; mi < 2; ++mi)
        fa[mi] = *(const bf16x8*)&lsA[(wm * 32 + mi * 16 + lr) * 64 + ks * 32 + lk];
#pragma unroll
      for (int nj = 0; nj < 2; ++nj)
        fb[nj] = *(const bf16x8*)&lsB[(wn * 32 + nj * 16 + lr) * 64 + ks * 32 + lk];
#pragma unroll
      for (int mi = 0; mi < 2; ++mi)
#pragma unroll
        for (int nj = 0; nj < 2; ++nj)
          acc[mi][nj] = mfma16(fa[mi], fb[nj], acc[mi][nj]);
    }
  }
  float* dst = sc + (size_t)bh * 4096;
#pragma unroll
  for (int mi = 0; mi < 2; ++mi)
#pragma unroll
    for (int nj = 0; nj < 2; ++nj)
#pragma unroll
      for (int r = 0; r < 4; ++r) {
        int d = wm * 32 + mi * 16 + lg * 4 + r;
        int e = wn * 32 + nj * 16 + lr;
        atomicAdd(&dst[d * 64 + e], acc[mi][nj][r]);
      }
}

// ---------------- phase B: Xo = spike(0.125 * Q @ scores) per (b,h) ----------------
// scores split exactly: hi = s & ~255, lo = s - hi (both exact in bf16) -> bit-exact.
__global__ __launch_bounds__(256) void phaseB_k(const u16* __restrict__ Qs,
                                                const float* __restrict__ sc,
                                                u16* __restrict__ Xo) {
  __shared__ u16 lsQ[128 * 64];
  __shared__ u16 sTh[64 * 64];
  __shared__ u16 sTl[64 * 64];
  const int t = threadIdx.x;
  const int mc = blockIdx.x, bh = blockIdx.y;
  const int b = bh >> 4, h = bh & 15;

  // load scores, split, store transposed sT[e][d] so B-frag k(=d) reads are contiguous
#pragma unroll
  for (int i = 0; i < 16; ++i) {
    int idx = i * 256 + t;
    int dd = idx >> 6, ee = idx & 63;
    float v = sc[(size_t)bh * 4096 + idx];
    int iv = (int)v;  // scores are exact integers
    int hi = iv & ~0xFF;
    sTh[ee * 64 + dd] = rne_bf16((float)hi);
    sTl[ee * 64 + dd] = rne_bf16((float)(iv - hi));
  }

  const int wv = t >> 6, ln = t & 63;
  const size_t qbase = ((size_t)(b * 4096 + mc * 128)) * 1024 + h * 64;
  const int srow = t >> 3, scol = (t & 7) << 3;
#pragma unroll
  for (int i = 0; i < 4; ++i)
    g2l16(Qs + qbase + (size_t)(i * 32 + srow) * 1024 + scol, lsQ + i * 2048 + wv * 512);
  __syncthreads();  // drains ds_writes (sT) and global_load_lds (lsQ)

  const int lr = ln & 15, lk = (ln >> 4) << 3, lg = ln >> 4;
  f32x4 acc[2][4] = {};
#pragma unroll
  for (int ks = 0; ks < 2; ++ks) {
    bf16x8 fa[2];
#pragma unroll
    for (int mi = 0; mi < 2; ++mi)
      fa[mi] = *(const bf16x8*)&lsQ[(wv * 32 + mi * 16 + lr) * 64 + ks * 32 + lk];
#pragma unroll
    for (int nj = 0; nj < 4; ++nj) {
      bf16x8 fh = *(const bf16x8*)&sTh[(nj * 16 + lr) * 64 + ks * 32 + lk];
      bf16x8 fl = *(const bf16x8*)&sTl[(nj * 16 + lr) * 64 + ks * 32 + lk];
#pragma unroll
      for (int mi = 0; mi < 2; ++mi) {
        acc[mi][nj] = mfma16(fa[mi], fh, acc[mi][nj]);
        acc[mi][nj] = mfma16(fa[mi], fl, acc[mi][nj]);
      }
    }
  }
#pragma unroll
  for (int mi = 0; mi < 2; ++mi)
#pragma unroll
    for (int nj = 0; nj < 4; ++nj)
#pragma unroll
      for (int r = 0; r < 4; ++r) {
        int tok = mc * 128 + wv * 32 + mi * 16 + lg * 4 + r;
        int e = nj * 16 + lr;
        float v = spikef(acc[mi][nj][r] * 0.125f);  // SCALE = 64^-0.5
        Xo[((size_t)(b * 4096 + tok)) * 1024 + h * 64 + e] = rne_bf16(v);
      }
}

// ---------------- host launch ----------------

extern "C" void kernel_launch(void* const* d_in, const int* in_sizes, int n_in,
                              void* d_out, int out_size, void* d_ws, size_t ws_size,
                              hipStream_t stream) {
  (void)in_sizes; (void)n_in; (void)out_size; (void)ws_size;

  const float* xin[3] = {(const float*)d_in[0], (const float*)d_in[1], (const float*)d_in[2]};
  const float* Wf[4] = {(const float*)d_in[3], (const float*)d_in[7],
                        (const float*)d_in[11], (const float*)d_in[15]};
  const float* Bf[4] = {(const float*)d_in[4], (const float*)d_in[8],
                        (const float*)d_in[12], (const float*)d_in[16]};
  const float* Sf[4] = {(const float*)d_in[5], (const float*)d_in[9],
                        (const float*)d_in[13], (const float*)d_in[17]};
  const float* Tf[4] = {(const float*)d_in[6], (const float*)d_in[10],
                        (const float*)d_in[14], (const float*)d_in[18]};

  char* ws = (char*)d_ws;
  const size_t MB = 1ull << 20;
  u16* whi[4];
  u16* wlo[4];
  for (int i = 0; i < 4; ++i) {
    whi[i] = (u16*)(ws + (size_t)i * 4 * MB);
    wlo[i] = (u16*)(ws + (size_t)i * 4 * MB + 2 * MB);
  }
  float* betas = (float*)(ws + 16 * MB);   // 4 x 1024 f32
  u16* Xbuf = (u16*)(ws + 18 * MB);        // 32MB: quantized input, later Xo
  u16* Qs   = (u16*)(ws + 50 * MB);        // 32MB (B,N,C) bf16
  u16* Ktp  = (u16*)(ws + 82 * MB);        // 32MB (B*H,64,4096) bf16
  u16* Vtp  = (u16*)(ws + 114 * MB);       // 32MB

  float* out0 = (float*)d_out;
  float* scores = out0 + 16777216;  // 4*16*64*64 = 262144 f32

  // weight split + fused affine
  for (int i = 0; i < 4; ++i) {
    wsplit_k<<<1024, 256, 0, stream>>>((const float4*)Wf[i], (us4*)whi[i], (us4*)wlo[i], 262144);
    beta_k<<<4, 256, 0, stream>>>(Bf[i], Sf[i], Tf[i], betas + i * 1024);
  }

  dim3 ggrid(128, 8);

  // Q path (single-bf16: downstream saturation masks rounding flips)
  quant_k<<<16384, 256, 0, stream>>>((const float4*)xin[0], (us4*)Xbuf, 4194304);
  gemm_k<0, false><<<ggrid, 256, 0, stream>>>(Xbuf, whi[0], nullptr, Sf[0], betas + 0, Qs);

  // K path (split-bf16: scores are validated directly -> need near-f32 precision)
  quant_k<<<16384, 256, 0, stream>>>((const float4*)xin[1], (us4*)Xbuf, 4194304);
  gemm_k<1, true><<<ggrid, 256, 0, stream>>>(Xbuf, whi[1], wlo[1], Sf[1], betas + 1024, Ktp);

  // V path (split-bf16)
  quant_k<<<16384, 256, 0, stream>>>((const float4*)xin[2], (us4*)Xbuf, 4194304);
  gemm_k<1, true><<<ggrid, 256, 0, stream>>>(Xbuf, whi[2], wlo[2], Sf[2], betas + 2048, Vtp);

  // scores (exact integers, deterministic atomics)
  hipMemsetAsync(scores, 0, 262144 * sizeof(float), stream);
  scores_k<<<dim3(4, 64), 256, 0, stream>>>(Ktp, Vtp, scores);

  // out = spike(Q @ scores * 0.125) -> Xbuf (reused as Xo)
  phaseB_k<<<dim3(32, 64), 256, 0, stream>>>(Qs, scores, Xbuf);

  // final conv_bn -> f32 d_out
  gemm_k<2, false><<<ggrid, 256, 0, stream>>>(Xbuf, whi[3], nullptr, Sf[3], betas + 3072,
                                              (void*)out0);
}

// Round 3
// 375.481 us; speedup vs baseline: 1.0969x; 1.0969x over previous
//
#include <hip/hip_runtime.h>

// MSMultiHeadAttentionBlock: spiking linear attention block on MI355X (gfx950)
// B=4, N=4096, C=1024, H=16, D=64. All I/O f32.
// R3 (= R2 resubmit after infra flake): 256^2-tile deep-pipelined GEMM
// (8 waves, BK=32, 4-slot LDS ring 128KB, counted vmcnt(8) gates, setprio,
// both-sides XOR swizzle). Split-weight GEMM as K'=2048 with B'=[W_hi|W_lo].

typedef __attribute__((ext_vector_type(8))) short bf16x8;
typedef __attribute__((ext_vector_type(4))) float f32x4;
typedef __attribute__((ext_vector_type(4))) unsigned short us4;
typedef unsigned short u16;
typedef unsigned int u32;

__device__ __forceinline__ u16 rne_bf16(float f) {
  u32 u = __float_as_uint(f);
  u += 0x7FFFu + ((u >> 16) & 1u);
  return (u16)(u >> 16);
}
__device__ __forceinline__ float bf16f(u16 h) { return __uint_as_float(((u32)h) << 16); }
// quant_spike forward: round-half-even(clamp(x,0,4)) — rintf is RNE, matches jnp.round
__device__ __forceinline__ float spikef(float v) { return rintf(fminf(fmaxf(v, 0.f), 4.f)); }

__device__ __forceinline__ void g2l16(const void* g, void* l) {
  // async global->LDS, 16B per lane; LDS dest = wave-uniform base + lane*16
  __builtin_amdgcn_global_load_lds((const __attribute__((address_space(1))) void*)g,
                                   (__attribute__((address_space(3))) void*)l, 16, 0, 0);
}

__device__ __forceinline__ f32x4 mfma16(bf16x8 a, bf16x8 b, f32x4 c) {
  return __builtin_amdgcn_mfma_f32_16x16x32_bf16(a, b, c, 0, 0, 0);
}

// ---------------- elementwise prep kernels ----------------

__global__ __launch_bounds__(256) void quant_k(const float4* __restrict__ in,
                                               us4* __restrict__ out, int n4) {
  int i = blockIdx.x * 256 + threadIdx.x;
  if (i >= n4) return;
  float4 v = in[i];
  us4 o;
  o[0] = rne_bf16(spikef(v.x));
  o[1] = rne_bf16(spikef(v.y));
  o[2] = rne_bf16(spikef(v.z));
  o[3] = rne_bf16(spikef(v.w));
  out[i] = o;
}

// w (1024x1024 f32) -> W2 (1024x2048 bf16): row n = [hi(n,0..1023) | lo(n,0..1023)]
__global__ __launch_bounds__(256) void wsplit_k(const float4* __restrict__ w,
                                                u16* __restrict__ W2) {
  int i = blockIdx.x * 256 + threadIdx.x;  // float4 index, 262144 total
  if (i >= 262144) return;
  float4 v = w[i];
  int flat = i * 4;
  int n = flat >> 10, c = flat & 1023;
  float cc[4] = {v.x, v.y, v.z, v.w};
  us4 h, l;
#pragma unroll
  for (int j = 0; j < 4; ++j) {
    u16 hb = rne_bf16(cc[j]);
    h[j] = hb;
    l[j] = rne_bf16(cc[j] - bf16f(hb));
  }
  *(us4*)&W2[(size_t)n * 2048 + c] = h;
  *(us4*)&W2[(size_t)n * 2048 + 1024 + c] = l;
}

__global__ __launch_bounds__(256) void beta_k(const float* __restrict__ b,
                                              const float* __restrict__ s,
                                              const float* __restrict__ t,
                                              float* __restrict__ beta) {
  int i = blockIdx.x * 256 + threadIdx.x;
  if (i < 1024) beta[i] = b[i] * s[i] + t[i];
}

// ---------------- 256^2 deep-pipelined GEMM ----------------
// C(16384 x 1024) = A(bf16, K=1024) x B'(bf16, row-stride 2048)^T, fused epilogue.
// NT = K-tiles of 32: 32 (hi only: Q/O) or 64 (hi then lo: K/V split).
// MODE 0: spike -> bf16 natural (B,N,C)   (Q)
// MODE 1: spike -> bf16 transposed (B,H,D,N)  (K/V)
// MODE 2: f32 natural, no spike            (O -> d_out)
template <int MODE, int NT>
__global__ __launch_bounds__(512) void gemm8_k(const u16* __restrict__ A,
                                               const u16* __restrict__ B,
                                               const float* __restrict__ alpha,
                                               const float* __restrict__ beta,
                                               void* __restrict__ outp) {
  constexpr int KB = 2048;               // B row stride
  __shared__ u16 lds[65536];             // 128 KiB: 4-slot ring x (A 16KB + B 16KB)
  const int t = threadIdx.x;
  const int w = t >> 6, ln = t & 63;
  const int wr = w >> 2, wc = w & 3;     // wave grid 2M x 4N
  const int lr = ln & 15, lg = ln >> 4;

  // XCD-aware block swizzle: 256 blocks, 2 XCDs per bn column
  const int lid = blockIdx.x;
  const int xcd = lid & 7, idx = lid >> 3;
  const int bm = ((xcd & 1) << 5) | idx;  // 0..63
  const int bn = xcd >> 1;                // 0..3

  const size_t abase = (size_t)(bm * 256) * 1024;
  const size_t bbase = (size_t)(bn * 256) * KB;
  // staging coords: thread t covers (row = c*128 + t>>2, 16B chunk slot = t&3);
  // source chunk pre-swizzled so LDS slot s holds global chunk s ^ ((row>>1)&3)
  const int srow = t >> 2;
  const int schunk = ((t & 3) ^ ((t >> 3) & 3)) * 8;  // u16 units
  const int ldst = w * 512;                           // per-wave LDS offset per call

  auto stageA = [&](int tile) {
    const int slot = (tile & 3) << 14;
    const int acol = (tile * 32) & 1023;  // K'=2048 wraps onto A's K=1024
#pragma unroll
    for (int c = 0; c < 2; ++c)
      g2l16(A + abase + (size_t)(c * 128 + srow) * 1024 + acol + schunk,
            lds + slot + c * 4096 + ldst);
  };
  auto stageB = [&](int tile) {
    const int slot = ((tile & 3) << 14) + 8192;
    const int bcol = tile * 32;
#pragma unroll
    for (int c = 0; c < 2; ++c)
      g2l16(B + bbase + (size_t)(c * 128 + srow) * KB + bcol + schunk,
            lds + slot + c * 4096 + ldst);
  };

  // prologue: 3 tiles in flight (12 loads/wave)
  stageA(0); stageB(0); stageA(1); stageB(1); stageA(2); stageB(2);

  // fragment read addressing (swizzled chunk is per-lane constant)
  const int rslot = (lg ^ ((lr >> 1) & 3)) * 8;  // u16
  const int arow = wr * 128 + lr;                // + mi*16
  const int brow = wc * 64 + lr;                 // + nj*16

  f32x4 acc[8][4] = {};

  asm volatile("s_waitcnt vmcnt(8)" ::: "memory");  // tile0 ready (8 younger in flight)
  __builtin_amdgcn_s_barrier();

#pragma unroll 1
  for (int tt = 0; tt < NT; ++tt) {
    const int sb = (tt & 3) << 14;
    const u16* As = lds + sb;
    const u16* Bs = lds + sb + 8192;
    // ---- PH0: read B frags + A mi0-3; stage A(tt+3); MFMA quadrant 0 ----
    bf16x8 bf[4], af[4];
#pragma unroll
    for (int nj = 0; nj < 4; ++nj)
      bf[nj] = *(const bf16x8*)&Bs[(brow + nj * 16) * 32 + rslot];
#pragma unroll
    for (int mi = 0; mi < 4; ++mi)
      af[mi] = *(const bf16x8*)&As[(arow + mi * 16) * 32 + rslot];
    if (tt < NT - 3) stageA(tt + 3);
    __builtin_amdgcn_sched_barrier(0);
    __builtin_amdgcn_s_barrier();
    __builtin_amdgcn_sched_barrier(0);
    __builtin_amdgcn_s_setprio(1);
#pragma unroll
    for (int mi = 0; mi < 4; ++mi)
#pragma unroll
      for (int nj = 0; nj < 4; ++nj)
        acc[mi][nj] = mfma16(af[mi], bf[nj], acc[mi][nj]);
    __builtin_amdgcn_s_setprio(0);
    __builtin_amdgcn_sched_barrier(0);
    __builtin_amdgcn_s_barrier();
    // ---- PH1: read A mi4-7; stage B(tt+3); MFMA quadrant 1; gate next tile ----
#pragma unroll
    for (int mi = 0; mi < 4; ++mi)
      af[mi] = *(const bf16x8*)&As[(arow + (mi + 4) * 16) * 32 + rslot];
    if (tt < NT - 3) stageB(tt + 3);
    __builtin_amdgcn_sched_barrier(0);
    __builtin_amdgcn_s_barrier();
    __builtin_amdgcn_sched_barrier(0);
    __builtin_amdgcn_s_setprio(1);
#pragma unroll
    for (int mi = 0; mi < 4; ++mi)
#pragma unroll
      for (int nj = 0; nj < 4; ++nj)
        acc[mi + 4][nj] = mfma16(af[mi], bf[nj], acc[mi + 4][nj]);
    __builtin_amdgcn_s_setprio(0);
    __builtin_amdgcn_sched_barrier(0);
    // counted gate for tile tt+1: vmcnt = 4 * (#younger tiles in flight)
    if (tt < NT - 3) {
      asm volatile("s_waitcnt vmcnt(8)" ::: "memory");
    } else if (tt == NT - 3) {
      asm volatile("s_waitcnt vmcnt(4)" ::: "memory");
    } else if (tt == NT - 2) {
      asm volatile("s_waitcnt vmcnt(0)" ::: "memory");
    }
    __builtin_amdgcn_s_barrier();
  }

  // ---- epilogue: val = acc*alpha[n] + beta[n] ----
#pragma unroll
  for (int nj = 0; nj < 4; ++nj) {
    const int gn = bn * 256 + wc * 64 + nj * 16 + lr;
    const float al = alpha[gn], be = beta[gn];
#pragma unroll
    for (int mi = 0; mi < 8; ++mi) {
      const int gm0 = bm * 256 + wr * 128 + mi * 16 + lg * 4;
      if constexpr (MODE == 0) {
        u16* o = (u16*)outp;
#pragma unroll
        for (int r = 0; r < 4; ++r) {
          float v = spikef(acc[mi][nj][r] * al + be);
          o[(size_t)(gm0 + r) * 1024 + gn] = rne_bf16(v);
        }
      } else if constexpr (MODE == 1) {
        u16* o = (u16*)outp;
        const int bi = gm0 >> 12, tok = gm0 & 4095;
        const int hh = gn >> 6, dd = gn & 63;
        us4 pack;
#pragma unroll
        for (int r = 0; r < 4; ++r)
          pack[r] = rne_bf16(spikef(acc[mi][nj][r] * al + be));
        *(us4*)&o[((size_t)((bi * 16 + hh) * 64 + dd)) * 4096 + tok] = pack;
      } else {
        float* o = (float*)outp;
#pragma unroll
        for (int r = 0; r < 4; ++r)
          o[(size_t)(gm0 + r) * 1024 + gn] = acc[mi][nj][r] * al + be;
      }
    }
  }
}

// ---------------- scores = K^T V per (b,h): 64x64, K-dim 4096 in 4 chunks ----------------
__global__ __launch_bounds__(256) void scores_k(const u16* __restrict__ Kt,
                                                const u16* __restrict__ Vt,
                                                float* __restrict__ sc) {
  __shared__ u16 lsA[64 * 64], lsB[64 * 64];
  const int t = threadIdx.x;
  const int bh = blockIdx.y, ck = blockIdx.x;
  const int wv = t >> 6, ln = t & 63;
  const int wm = wv & 1, wn = wv >> 1;
  const int lr = ln & 15, lk = (ln >> 4) << 3, lg = ln >> 4;
  const size_t base = (size_t)bh * 64 * 4096 + (size_t)ck * 1024;
  f32x4 acc[2][2] = {};
  const int srow = t >> 3;        // 0..31
  const int scol = (t & 7) << 3;  // 0..56

  for (int kt = 0; kt < 16; ++kt) {
    __syncthreads();
#pragma unroll
    for (int i = 0; i < 2; ++i) {
      g2l16(Kt + base + (size_t)(i * 32 + srow) * 4096 + kt * 64 + scol,
            lsA + i * 2048 + wv * 512);
      g2l16(Vt + base + (size_t)(i * 32 + srow) * 4096 + kt * 64 + scol,
            lsB + i * 2048 + wv * 512);
    }
    __syncthreads();
#pragma unroll
    for (int ks = 0; ks < 2; ++ks) {
      bf16x8 fa[2], fb[2];
#pragma unroll
      for (int mi = 0; mi < 2; ++mi)
        fa[mi] = *(const bf16x8*)&lsA[(wm * 32 + mi * 16 + lr) * 64 + ks * 32 + lk];
#pragma unroll
      for (int nj = 0; nj < 2; ++nj)
        fb[nj] = *(const bf16x8*)&lsB[(wn * 32 + nj * 16 + lr) * 64 + ks * 32 + lk];
#pragma unroll
      for (int mi = 0; mi < 2; ++mi)
#pragma unroll
        for (int nj = 0; nj < 2; ++nj)
          acc[mi][nj] = mfma16(fa[mi], fb[nj], acc[mi][nj]);
    }
  }
  float* dst = sc + (size_t)bh * 4096;
#pragma unroll
  for (int mi = 0; mi < 2; ++mi)
#pragma unroll
    for (int nj = 0; nj < 2; ++nj)
#pragma unroll
      for (int r = 0; r < 4; ++r) {
        int d = wm * 32 + mi * 16 + lg * 4 + r;
        int e = wn * 32 + nj * 16 + lr;
        atomicAdd(&dst[d * 64 + e], acc[mi][nj][r]);
      }
}

// ---------------- phase B: Xo = spike(0.125 * Q @ scores) per (b,h) ----------------
__global__ __launch_bounds__(256) void phaseB_k(const u16* __restrict__ Qs,
                                                const float* __restrict__ sc,
                                                u16* __restrict__ Xo) {
  __shared__ u16 lsQ[128 * 64];
  __shared__ u16 sTh[64 * 64];
  __shared__ u16 sTl[64 * 64];
  const int t = threadIdx.x;
  const int mc = blockIdx.x, bh = blockIdx.y;
  const int b = bh >> 4, h = bh & 15;

#pragma unroll
  for (int i = 0; i < 16; ++i) {
    int idx = i * 256 + t;
    int dd = idx >> 6, ee = idx & 63;
    float v = sc[(size_t)bh * 4096 + idx];
    int iv = (int)v;  // scores are exact integers
    int hi = iv & ~0xFF;
    sTh[ee * 64 + dd] = rne_bf16((float)hi);
    sTl[ee * 64 + dd] = rne_bf16((float)(iv - hi));
  }

  const int wv = t >> 6, ln = t & 63;
  const size_t qbase = ((size_t)(b * 4096 + mc * 128)) * 1024 + h * 64;
  const int srow = t >> 3, scol = (t & 7) << 3;
#pragma unroll
  for (int i = 0; i < 4; ++i)
    g2l16(Qs + qbase + (size_t)(i * 32 + srow) * 1024 + scol, lsQ + i * 2048 + wv * 512);
  __syncthreads();

  const int lr = ln & 15, lk = (ln >> 4) << 3, lg = ln >> 4;
  f32x4 acc[2][4] = {};
#pragma unroll
  for (int ks = 0; ks < 2; ++ks) {
    bf16x8 fa[2];
#pragma unroll
    for (int mi = 0; mi < 2; ++mi)
      fa[mi] = *(const bf16x8*)&lsQ[(wv * 32 + mi * 16 + lr) * 64 + ks * 32 + lk];
#pragma unroll
    for (int nj = 0; nj < 4; ++nj) {
      bf16x8 fh = *(const bf16x8*)&sTh[(nj * 16 + lr) * 64 + ks * 32 + lk];
      bf16x8 fl = *(const bf16x8*)&sTl[(nj * 16 + lr) * 64 + ks * 32 + lk];
#pragma unroll
      for (int mi = 0; mi < 2; ++mi) {
        acc[mi][nj] = mfma16(fa[mi], fh, acc[mi][nj]);
        acc[mi][nj] = mfma16(fa[mi], fl, acc[mi][nj]);
      }
    }
  }
#pragma unroll
  for (int mi = 0; mi < 2; ++mi)
#pragma unroll
    for (int nj = 0; nj < 4; ++nj)
#pragma unroll
      for (int r = 0; r < 4; ++r) {
        int tok = mc * 128 + wv * 32 + mi * 16 + lg * 4 + r;
        int e = nj * 16 + lr;
        float v = spikef(acc[mi][nj][r] * 0.125f);  // SCALE = 64^-0.5
        Xo[((size_t)(b * 4096 + tok)) * 1024 + h * 64 + e] = rne_bf16(v);
      }
}

// ---------------- host launch ----------------

extern "C" void kernel_launch(void* const* d_in, const int* in_sizes, int n_in,
                              void* d_out, int out_size, void* d_ws, size_t ws_size,
                              hipStream_t stream) {
  (void)in_sizes; (void)n_in; (void)out_size; (void)ws_size;

  const float* xin[3] = {(const float*)d_in[0], (const float*)d_in[1], (const float*)d_in[2]};
  const float* Wf[4] = {(const float*)d_in[3], (const float*)d_in[7],
                        (const float*)d_in[11], (const float*)d_in[15]};
  const float* Bf[4] = {(const float*)d_in[4], (const float*)d_in[8],
                        (const float*)d_in[12], (const float*)d_in[16]};
  const float* Sf[4] = {(const float*)d_in[5], (const float*)d_in[9],
                        (const float*)d_in[13], (const float*)d_in[17]};
  const float* Tf[4] = {(const float*)d_in[6], (const float*)d_in[10],
                        (const float*)d_in[14], (const float*)d_in[18]};

  char* ws = (char*)d_ws;
  const size_t MB = 1ull << 20;
  u16* W2[4];
  for (int i = 0; i < 4; ++i) W2[i] = (u16*)(ws + (size_t)i * 4 * MB);  // 1024x2048 bf16
  float* betas = (float*)(ws + 16 * MB);   // 4 x 1024 f32
  u16* Xbuf = (u16*)(ws + 18 * MB);        // 32MB: quantized input, later Xo
  u16* Qs   = (u16*)(ws + 50 * MB);        // 32MB (B,N,C) bf16
  u16* Ktp  = (u16*)(ws + 82 * MB);        // 32MB (B*H,64,4096) bf16
  u16* Vtp  = (u16*)(ws + 114 * MB);       // 32MB

  float* out0 = (float*)d_out;
  float* scores = out0 + 16777216;  // 4*16*64*64 = 262144 f32

  for (int i = 0; i < 4; ++i) {
    wsplit_k<<<1024, 256, 0, stream>>>((const float4*)Wf[i], W2[i]);
    beta_k<<<4, 256, 0, stream>>>(Bf[i], Sf[i], Tf[i], betas + i * 1024);
  }

  // Q path (hi weights only: downstream saturation masks rounding flips)
  quant_k<<<16384, 256, 0, stream>>>((const float4*)xin[0], (us4*)Xbuf, 4194304);
  gemm8_k<0, 32><<<256, 512, 0, stream>>>(Xbuf, W2[0], Sf[0], betas + 0, Qs);

  // K path (split hi+lo: scores validated directly -> near-f32 precision)
  quant_k<<<16384, 256, 0, stream>>>((const float4*)xin[1], (us4*)Xbuf, 4194304);
  gemm8_k<1, 64><<<256, 512, 0, stream>>>(Xbuf, W2[1], Sf[1], betas + 1024, Ktp);

  // V path (split hi+lo)
  quant_k<<<16384, 256, 0, stream>>>((const float4*)xin[2], (us4*)Xbuf, 4194304);
  gemm8_k<1, 64><<<256, 512, 0, stream>>>(Xbuf, W2[2], Sf[2], betas + 2048, Vtp);

  // scores (exact integers, deterministic atomics)
  hipMemsetAsync(scores, 0, 262144 * sizeof(float), stream);
  scores_k<<<dim3(4, 64), 256, 0, stream>>>(Ktp, Vtp, scores);

  // out = spike(Q @ scores * 0.125) -> Xbuf (reused as Xo)
  phaseB_k<<<dim3(32, 64), 256, 0, stream>>>(Qs, scores, Xbuf);

  // final conv_bn -> f32 d_out
  gemm8_k<2, 32><<<256, 512, 0, stream>>>(Xbuf, W2[3], Sf[3], betas + 3072, (void*)out0);
}

// Round 4
// 352.788 us; speedup vs baseline: 1.1675x; 1.0643x over previous
//
#include <hip/hip_runtime.h>

// MSMultiHeadAttentionBlock: spiking linear attention block on MI355X (gfx950)
// B=4, N=4096, C=1024, H=16, D=64. All I/O f32.
// R4: R3 + XCD-GROUPED block swizzle: the 4 bn-blocks sharing an A-panel (same
// bm) are co-resident on ONE XCD -> A-panel fetched once per L2 instead of 4x.
// (R3 had bn = xcd>>1, spreading A-sharers across 4 XCDs: FETCH_SIZE 135 MB.)

typedef __attribute__((ext_vector_type(8))) short bf16x8;
typedef __attribute__((ext_vector_type(4))) float f32x4;
typedef __attribute__((ext_vector_type(4))) unsigned short us4;
typedef unsigned short u16;
typedef unsigned int u32;

__device__ __forceinline__ u16 rne_bf16(float f) {
  u32 u = __float_as_uint(f);
  u += 0x7FFFu + ((u >> 16) & 1u);
  return (u16)(u >> 16);
}
__device__ __forceinline__ float bf16f(u16 h) { return __uint_as_float(((u32)h) << 16); }
// quant_spike forward: round-half-even(clamp(x,0,4)) — rintf is RNE, matches jnp.round
__device__ __forceinline__ float spikef(float v) { return rintf(fminf(fmaxf(v, 0.f), 4.f)); }

__device__ __forceinline__ void g2l16(const void* g, void* l) {
  // async global->LDS, 16B per lane; LDS dest = wave-uniform base + lane*16
  __builtin_amdgcn_global_load_lds((const __attribute__((address_space(1))) void*)g,
                                   (__attribute__((address_space(3))) void*)l, 16, 0, 0);
}

__device__ __forceinline__ f32x4 mfma16(bf16x8 a, bf16x8 b, f32x4 c) {
  return __builtin_amdgcn_mfma_f32_16x16x32_bf16(a, b, c, 0, 0, 0);
}

// ---------------- elementwise prep kernels ----------------

__global__ __launch_bounds__(256) void quant_k(const float4* __restrict__ in,
                                               us4* __restrict__ out, int n4) {
  int i = blockIdx.x * 256 + threadIdx.x;
  if (i >= n4) return;
  float4 v = in[i];
  us4 o;
  o[0] = rne_bf16(spikef(v.x));
  o[1] = rne_bf16(spikef(v.y));
  o[2] = rne_bf16(spikef(v.z));
  o[3] = rne_bf16(spikef(v.w));
  out[i] = o;
}

// w (1024x1024 f32) -> W2 (1024x2048 bf16): row n = [hi(n,0..1023) | lo(n,0..1023)]
__global__ __launch_bounds__(256) void wsplit_k(const float4* __restrict__ w,
                                                u16* __restrict__ W2) {
  int i = blockIdx.x * 256 + threadIdx.x;  // float4 index, 262144 total
  if (i >= 262144) return;
  float4 v = w[i];
  int flat = i * 4;
  int n = flat >> 10, c = flat & 1023;
  float cc[4] = {v.x, v.y, v.z, v.w};
  us4 h, l;
#pragma unroll
  for (int j = 0; j < 4; ++j) {
    u16 hb = rne_bf16(cc[j]);
    h[j] = hb;
    l[j] = rne_bf16(cc[j] - bf16f(hb));
  }
  *(us4*)&W2[(size_t)n * 2048 + c] = h;
  *(us4*)&W2[(size_t)n * 2048 + 1024 + c] = l;
}

__global__ __launch_bounds__(256) void beta_k(const float* __restrict__ b,
                                              const float* __restrict__ s,
                                              const float* __restrict__ t,
                                              float* __restrict__ beta) {
  int i = blockIdx.x * 256 + threadIdx.x;
  if (i < 1024) beta[i] = b[i] * s[i] + t[i];
}

// ---------------- 256^2 deep-pipelined GEMM ----------------
// C(16384 x 1024) = A(bf16, K=1024) x B'(bf16, row-stride 2048)^T, fused epilogue.
// NT = K-tiles of 32: 32 (hi only: Q/O) or 64 (hi then lo: K/V split).
// MODE 0: spike -> bf16 natural (B,N,C)   (Q)
// MODE 1: spike -> bf16 transposed (B,H,D,N)  (K/V)
// MODE 2: f32 natural, no spike            (O -> d_out)
template <int MODE, int NT>
__global__ __launch_bounds__(512) void gemm8_k(const u16* __restrict__ A,
                                               const u16* __restrict__ B,
                                               const float* __restrict__ alpha,
                                               const float* __restrict__ beta,
                                               void* __restrict__ outp) {
  constexpr int KB = 2048;               // B row stride
  __shared__ u16 lds[65536];             // 128 KiB: 4-slot ring x (A 16KB + B 16KB)
  const int t = threadIdx.x;
  const int w = t >> 6, ln = t & 63;
  const int wr = w >> 2, wc = w & 3;     // wave grid 2M x 4N
  const int lr = ln & 15, lg = ln >> 4;

  // XCD-GROUPED swizzle: dispatch round-robins XCDs (xcd = lid&7); give each
  // XCD a contiguous 8-panel bm range x ALL 4 bn -> A-panel L2 reuse on-die.
  const int lid = blockIdx.x;
  const int xcd = lid & 7, idx = lid >> 3;  // idx 0..31 within XCD
  const int bm = xcd * 8 + (idx >> 2);      // 0..63
  const int bn = idx & 3;                   // 0..3

  const size_t abase = (size_t)(bm * 256) * 1024;
  const size_t bbase = (size_t)(bn * 256) * KB;
  // staging coords: thread t covers (row = c*128 + t>>2, 16B chunk slot = t&3);
  // source chunk pre-swizzled so LDS slot s holds global chunk s ^ ((row>>1)&3)
  const int srow = t >> 2;
  const int schunk = ((t & 3) ^ ((t >> 3) & 3)) * 8;  // u16 units
  const int ldst = w * 512;                           // per-wave LDS offset per call

  auto stageA = [&](int tile) {
    const int slot = (tile & 3) << 14;
    const int acol = (tile * 32) & 1023;  // K'=2048 wraps onto A's K=1024
#pragma unroll
    for (int c = 0; c < 2; ++c)
      g2l16(A + abase + (size_t)(c * 128 + srow) * 1024 + acol + schunk,
            lds + slot + c * 4096 + ldst);
  };
  auto stageB = [&](int tile) {
    const int slot = ((tile & 3) << 14) + 8192;
    const int bcol = tile * 32;
#pragma unroll
    for (int c = 0; c < 2; ++c)
      g2l16(B + bbase + (size_t)(c * 128 + srow) * KB + bcol + schunk,
            lds + slot + c * 4096 + ldst);
  };

  // prologue: 3 tiles in flight (12 loads/wave)
  stageA(0); stageB(0); stageA(1); stageB(1); stageA(2); stageB(2);

  // fragment read addressing (swizzled chunk is per-lane constant)
  const int rslot = (lg ^ ((lr >> 1) & 3)) * 8;  // u16
  const int arow = wr * 128 + lr;                // + mi*16
  const int brow = wc * 64 + lr;                 // + nj*16

  f32x4 acc[8][4] = {};

  asm volatile("s_waitcnt vmcnt(8)" ::: "memory");  // tile0 ready (8 younger in flight)
  __builtin_amdgcn_s_barrier();

#pragma unroll 1
  for (int tt = 0; tt < NT; ++tt) {
    const int sb = (tt & 3) << 14;
    const u16* As = lds + sb;
    const u16* Bs = lds + sb + 8192;
    // ---- PH0: read B frags + A mi0-3; stage A(tt+3); MFMA quadrant 0 ----
    bf16x8 bf[4], af[4];
#pragma unroll
    for (int nj = 0; nj < 4; ++nj)
      bf[nj] = *(const bf16x8*)&Bs[(brow + nj * 16) * 32 + rslot];
#pragma unroll
    for (int mi = 0; mi < 4; ++mi)
      af[mi] = *(const bf16x8*)&As[(arow + mi * 16) * 32 + rslot];
    if (tt < NT - 3) stageA(tt + 3);
    __builtin_amdgcn_sched_barrier(0);
    __builtin_amdgcn_s_barrier();
    __builtin_amdgcn_sched_barrier(0);
    __builtin_amdgcn_s_setprio(1);
#pragma unroll
    for (int mi = 0; mi < 4; ++mi)
#pragma unroll
      for (int nj = 0; nj < 4; ++nj)
        acc[mi][nj] = mfma16(af[mi], bf[nj], acc[mi][nj]);
    __builtin_amdgcn_s_setprio(0);
    __builtin_amdgcn_sched_barrier(0);
    __builtin_amdgcn_s_barrier();
    // ---- PH1: read A mi4-7; stage B(tt+3); MFMA quadrant 1; gate next tile ----
#pragma unroll
    for (int mi = 0; mi < 4; ++mi)
      af[mi] = *(const bf16x8*)&As[(arow + (mi + 4) * 16) * 32 + rslot];
    if (tt < NT - 3) stageB(tt + 3);
    __builtin_amdgcn_sched_barrier(0);
    __builtin_amdgcn_s_barrier();
    __builtin_amdgcn_sched_barrier(0);
    __builtin_amdgcn_s_setprio(1);
#pragma unroll
    for (int mi = 0; mi < 4; ++mi)
#pragma unroll
      for (int nj = 0; nj < 4; ++nj)
        acc[mi + 4][nj] = mfma16(af[mi], bf[nj], acc[mi + 4][nj]);
    __builtin_amdgcn_s_setprio(0);
    __builtin_amdgcn_sched_barrier(0);
    // counted gate for tile tt+1: vmcnt = 4 * (#younger tiles in flight)
    if (tt < NT - 3) {
      asm volatile("s_waitcnt vmcnt(8)" ::: "memory");
    } else if (tt == NT - 3) {
      asm volatile("s_waitcnt vmcnt(4)" ::: "memory");
    } else if (tt == NT - 2) {
      asm volatile("s_waitcnt vmcnt(0)" ::: "memory");
    }
    __builtin_amdgcn_s_barrier();
  }

  // ---- epilogue: val = acc*alpha[n] + beta[n] ----
#pragma unroll
  for (int nj = 0; nj < 4; ++nj) {
    const int gn = bn * 256 + wc * 64 + nj * 16 + lr;
    const float al = alpha[gn], be = beta[gn];
#pragma unroll
    for (int mi = 0; mi < 8; ++mi) {
      const int gm0 = bm * 256 + wr * 128 + mi * 16 + lg * 4;
      if constexpr (MODE == 0) {
        u16* o = (u16*)outp;
#pragma unroll
        for (int r = 0; r < 4; ++r) {
          float v = spikef(acc[mi][nj][r] * al + be);
          o[(size_t)(gm0 + r) * 1024 + gn] = rne_bf16(v);
        }
      } else if constexpr (MODE == 1) {
        u16* o = (u16*)outp;
        const int bi = gm0 >> 12, tok = gm0 & 4095;
        const int hh = gn >> 6, dd = gn & 63;
        us4 pack;
#pragma unroll
        for (int r = 0; r < 4; ++r)
          pack[r] = rne_bf16(spikef(acc[mi][nj][r] * al + be));
        *(us4*)&o[((size_t)((bi * 16 + hh) * 64 + dd)) * 4096 + tok] = pack;
      } else {
        float* o = (float*)outp;
#pragma unroll
        for (int r = 0; r < 4; ++r)
          o[(size_t)(gm0 + r) * 1024 + gn] = acc[mi][nj][r] * al + be;
      }
    }
  }
}

// ---------------- scores = K^T V per (b,h): 64x64, K-dim 4096 in 4 chunks ----------------
__global__ __launch_bounds__(256) void scores_k(const u16* __restrict__ Kt,
                                                const u16* __restrict__ Vt,
                                                float* __restrict__ sc) {
  __shared__ u16 lsA[64 * 64], lsB[64 * 64];
  const int t = threadIdx.x;
  const int bh = blockIdx.y, ck = blockIdx.x;
  const int wv = t >> 6, ln = t & 63;
  const int wm = wv & 1, wn = wv >> 1;
  const int lr = ln & 15, lk = (ln >> 4) << 3, lg = ln >> 4;
  const size_t base = (size_t)bh * 64 * 4096 + (size_t)ck * 1024;
  f32x4 acc[2][2] = {};
  const int srow = t >> 3;        // 0..31
  const int scol = (t & 7) << 3;  // 0..56

  for (int kt = 0; kt < 16; ++kt) {
    __syncthreads();
#pragma unroll
    for (int i = 0; i < 2; ++i) {
      g2l16(Kt + base + (size_t)(i * 32 + srow) * 4096 + kt * 64 + scol,
            lsA + i * 2048 + wv * 512);
      g2l16(Vt + base + (size_t)(i * 32 + srow) * 4096 + kt * 64 + scol,
            lsB + i * 2048 + wv * 512);
    }
    __syncthreads();
#pragma unroll
    for (int ks = 0; ks < 2; ++ks) {
      bf16x8 fa[2], fb[2];
#pragma unroll
      for (int mi = 0; mi < 2; ++mi)
        fa[mi] = *(const bf16x8*)&lsA[(wm * 32 + mi * 16 + lr) * 64 + ks * 32 + lk];
#pragma unroll
      for (int nj = 0; nj < 2; ++nj)
        fb[nj] = *(const bf16x8*)&lsB[(wn * 32 + nj * 16 + lr) * 64 + ks * 32 + lk];
#pragma unroll
      for (int mi = 0; mi < 2; ++mi)
#pragma unroll
        for (int nj = 0; nj < 2; ++nj)
          acc[mi][nj] = mfma16(fa[mi], fb[nj], acc[mi][nj]);
    }
  }
  float* dst = sc + (size_t)bh * 4096;
#pragma unroll
  for (int mi = 0; mi < 2; ++mi)
#pragma unroll
    for (int nj = 0; nj < 2; ++nj)
#pragma unroll
      for (int r = 0; r < 4; ++r) {
        int d = wm * 32 + mi * 16 + lg * 4 + r;
        int e = wn * 32 + nj * 16 + lr;
        atomicAdd(&dst[d * 64 + e], acc[mi][nj][r]);
      }
}

// ---------------- phase B: Xo = spike(0.125 * Q @ scores) per (b,h) ----------------
__global__ __launch_bounds__(256) void phaseB_k(const u16* __restrict__ Qs,
                                                const float* __restrict__ sc,
                                                u16* __restrict__ Xo) {
  __shared__ u16 lsQ[128 * 64];
  __shared__ u16 sTh[64 * 64];
  __shared__ u16 sTl[64 * 64];
  const int t = threadIdx.x;
  const int mc = blockIdx.x, bh = blockIdx.y;
  const int b = bh >> 4, h = bh & 15;

#pragma unroll
  for (int i = 0; i < 16; ++i) {
    int idx = i * 256 + t;
    int dd = idx >> 6, ee = idx & 63;
    float v = sc[(size_t)bh * 4096 + idx];
    int iv = (int)v;  // scores are exact integers
    int hi = iv & ~0xFF;
    sTh[ee * 64 + dd] = rne_bf16((float)hi);
    sTl[ee * 64 + dd] = rne_bf16((float)(iv - hi));
  }

  const int wv = t >> 6, ln = t & 63;
  const size_t qbase = ((size_t)(b * 4096 + mc * 128)) * 1024 + h * 64;
  const int srow = t >> 3, scol = (t & 7) << 3;
#pragma unroll
  for (int i = 0; i < 4; ++i)
    g2l16(Qs + qbase + (size_t)(i * 32 + srow) * 1024 + scol, lsQ + i * 2048 + wv * 512);
  __syncthreads();

  const int lr = ln & 15, lk = (ln >> 4) << 3, lg = ln >> 4;
  f32x4 acc[2][4] = {};
#pragma unroll
  for (int ks = 0; ks < 2; ++ks) {
    bf16x8 fa[2];
#pragma unroll
    for (int mi = 0; mi < 2; ++mi)
      fa[mi] = *(const bf16x8*)&lsQ[(wv * 32 + mi * 16 + lr) * 64 + ks * 32 + lk];
#pragma unroll
    for (int nj = 0; nj < 4; ++nj) {
      bf16x8 fh = *(const bf16x8*)&sTh[(nj * 16 + lr) * 64 + ks * 32 + lk];
      bf16x8 fl = *(const bf16x8*)&sTl[(nj * 16 + lr) * 64 + ks * 32 + lk];
#pragma unroll
      for (int mi = 0; mi < 2; ++mi) {
        acc[mi][nj] = mfma16(fa[mi], fh, acc[mi][nj]);
        acc[mi][nj] = mfma16(fa[mi], fl, acc[mi][nj]);
      }
    }
  }
#pragma unroll
  for (int mi = 0; mi < 2; ++mi)
#pragma unroll
    for (int nj = 0; nj < 4; ++nj)
#pragma unroll
      for (int r = 0; r < 4; ++r) {
        int tok = mc * 128 + wv * 32 + mi * 16 + lg * 4 + r;
        int e = nj * 16 + lr;
        float v = spikef(acc[mi][nj][r] * 0.125f);  // SCALE = 64^-0.5
        Xo[((size_t)(b * 4096 + tok)) * 1024 + h * 64 + e] = rne_bf16(v);
      }
}

// ---------------- host launch ----------------

extern "C" void kernel_launch(void* const* d_in, const int* in_sizes, int n_in,
                              void* d_out, int out_size, void* d_ws, size_t ws_size,
                              hipStream_t stream) {
  (void)in_sizes; (void)n_in; (void)out_size; (void)ws_size;

  const float* xin[3] = {(const float*)d_in[0], (const float*)d_in[1], (const float*)d_in[2]};
  const float* Wf[4] = {(const float*)d_in[3], (const float*)d_in[7],
                        (const float*)d_in[11], (const float*)d_in[15]};
  const float* Bf[4] = {(const float*)d_in[4], (const float*)d_in[8],
                        (const float*)d_in[12], (const float*)d_in[16]};
  const float* Sf[4] = {(const float*)d_in[5], (const float*)d_in[9],
                        (const float*)d_in[13], (const float*)d_in[17]};
  const float* Tf[4] = {(const float*)d_in[6], (const float*)d_in[10],
                        (const float*)d_in[14], (const float*)d_in[18]};

  char* ws = (char*)d_ws;
  const size_t MB = 1ull << 20;
  u16* W2[4];
  for (int i = 0; i < 4; ++i) W2[i] = (u16*)(ws + (size_t)i * 4 * MB);  // 1024x2048 bf16
  float* betas = (float*)(ws + 16 * MB);   // 4 x 1024 f32
  u16* Xbuf = (u16*)(ws + 18 * MB);        // 32MB: quantized input, later Xo
  u16* Qs   = (u16*)(ws + 50 * MB);        // 32MB (B,N,C) bf16
  u16* Ktp  = (u16*)(ws + 82 * MB);        // 32MB (B*H,64,4096) bf16
  u16* Vtp  = (u16*)(ws + 114 * MB);       // 32MB

  float* out0 = (float*)d_out;
  float* scores = out0 + 16777216;  // 4*16*64*64 = 262144 f32

  for (int i = 0; i < 4; ++i) {
    wsplit_k<<<1024, 256, 0, stream>>>((const float4*)Wf[i], W2[i]);
    beta_k<<<4, 256, 0, stream>>>(Bf[i], Sf[i], Tf[i], betas + i * 1024);
  }

  // Q path (hi weights only: downstream saturation masks rounding flips)
  quant_k<<<16384, 256, 0, stream>>>((const float4*)xin[0], (us4*)Xbuf, 4194304);
  gemm8_k<0, 32><<<256, 512, 0, stream>>>(Xbuf, W2[0], Sf[0], betas + 0, Qs);

  // K path (split hi+lo: scores validated directly -> near-f32 precision)
  quant_k<<<16384, 256, 0, stream>>>((const float4*)xin[1], (us4*)Xbuf, 4194304);
  gemm8_k<1, 64><<<256, 512, 0, stream>>>(Xbuf, W2[1], Sf[1], betas + 1024, Ktp);

  // V path (split hi+lo)
  quant_k<<<16384, 256, 0, stream>>>((const float4*)xin[2], (us4*)Xbuf, 4194304);
  gemm8_k<1, 64><<<256, 512, 0, stream>>>(Xbuf, W2[2], Sf[2], betas + 2048, Vtp);

  // scores (exact integers, deterministic atomics)
  hipMemsetAsync(scores, 0, 262144 * sizeof(float), stream);
  scores_k<<<dim3(4, 64), 256, 0, stream>>>(Ktp, Vtp, scores);

  // out = spike(Q @ scores * 0.125) -> Xbuf (reused as Xo)
  phaseB_k<<<dim3(32, 64), 256, 0, stream>>>(Qs, scores, Xbuf);

  // final conv_bn -> f32 d_out
  gemm8_k<2, 32><<<256, 512, 0, stream>>>(Xbuf, W2[3], Sf[3], betas + 3072, (void*)out0);
}

// Round 5
// 343.535 us; speedup vs baseline: 1.1989x; 1.0269x over previous
//
#include <hip/hip_runtime.h>

// MSMultiHeadAttentionBlock: spiking linear attention block on MI355X (gfx950)
// B=4, N=4096, C=1024, H=16, D=64. All I/O f32.
// R5: GEMM rebuilt on the m201 8-phase schedule: BK=64, depth-2 LDS dbuf
// (128KB), 4 phases per K64-tile (16 MFMA each, quadrant order (0,0),(1,0),
// (1,1),(0,1) with frag reuse), staged halves {P1:Bh1(t+1), P3:Ah0(t+2),
// P4:Ah1+Bh0(t+2)}, ONE counted vmcnt(6) gate per tile, lgkmcnt(8) throttle,
// setprio. Swizzle: chunk ^= row&7 both sides (reads 2-way = free).
// Split-weight GEMM stays K'=2048 with B'=[W_hi|W_lo]; XCD-grouped blocks (R4).

typedef __attribute__((ext_vector_type(8))) short bf16x8;
typedef __attribute__((ext_vector_type(4))) float f32x4;
typedef __attribute__((ext_vector_type(4))) unsigned short us4;
typedef unsigned short u16;
typedef unsigned int u32;

__device__ __forceinline__ u16 rne_bf16(float f) {
  u32 u = __float_as_uint(f);
  u += 0x7FFFu + ((u >> 16) & 1u);
  return (u16)(u >> 16);
}
__device__ __forceinline__ float bf16f(u16 h) { return __uint_as_float(((u32)h) << 16); }
// quant_spike forward: round-half-even(clamp(x,0,4)) — rintf is RNE, matches jnp.round
__device__ __forceinline__ float spikef(float v) { return rintf(fminf(fmaxf(v, 0.f), 4.f)); }

__device__ __forceinline__ void g2l16(const void* g, void* l) {
  // async global->LDS, 16B per lane; LDS dest = wave-uniform base + lane*16
  __builtin_amdgcn_global_load_lds((const __attribute__((address_space(1))) void*)g,
                                   (__attribute__((address_space(3))) void*)l, 16, 0, 0);
}

__device__ __forceinline__ f32x4 mfma16(bf16x8 a, bf16x8 b, f32x4 c) {
  return __builtin_amdgcn_mfma_f32_16x16x32_bf16(a, b, c, 0, 0, 0);
}

// ---------------- elementwise prep kernels ----------------

__global__ __launch_bounds__(256) void quant_k(const float4* __restrict__ in,
                                               us4* __restrict__ out, int n4) {
  int i = blockIdx.x * 256 + threadIdx.x;
  if (i >= n4) return;
  float4 v = in[i];
  us4 o;
  o[0] = rne_bf16(spikef(v.x));
  o[1] = rne_bf16(spikef(v.y));
  o[2] = rne_bf16(spikef(v.z));
  o[3] = rne_bf16(spikef(v.w));
  out[i] = o;
}

// w (1024x1024 f32) -> W2 (1024x2048 bf16): row n = [hi(n,0..1023) | lo(n,0..1023)]
__global__ __launch_bounds__(256) void wsplit_k(const float4* __restrict__ w,
                                                u16* __restrict__ W2) {
  int i = blockIdx.x * 256 + threadIdx.x;  // float4 index, 262144 total
  if (i >= 262144) return;
  float4 v = w[i];
  int flat = i * 4;
  int n = flat >> 10, c = flat & 1023;
  float cc[4] = {v.x, v.y, v.z, v.w};
  us4 h, l;
#pragma unroll
  for (int j = 0; j < 4; ++j) {
    u16 hb = rne_bf16(cc[j]);
    h[j] = hb;
    l[j] = rne_bf16(cc[j] - bf16f(hb));
  }
  *(us4*)&W2[(size_t)n * 2048 + c] = h;
  *(us4*)&W2[(size_t)n * 2048 + 1024 + c] = l;
}

__global__ __launch_bounds__(256) void beta_k(const float* __restrict__ b,
                                              const float* __restrict__ s,
                                              const float* __restrict__ t,
                                              float* __restrict__ beta) {
  int i = blockIdx.x * 256 + threadIdx.x;
  if (i < 1024) beta[i] = b[i] * s[i] + t[i];
}

// ---------------- 256^2 8-phase GEMM (m201 schedule) ----------------
// C(16384 x 1024) = A(bf16, K=1024) x B'(bf16, row-stride 2048)^T, fused epilogue.
// NT = K-tiles of 64: 32 (split hi+lo: K/V) or 16 (hi only: Q/O).
// MODE 0: spike -> bf16 natural (B,N,C)   (Q)
// MODE 1: spike -> bf16 transposed (B,H,D,N)  (K/V)
// MODE 2: f32 natural, no spike            (O -> d_out)
//
// LDS (u16 units): buf b at b*32768; A-half h at +h*8192; B-half h at +16384+h*8192.
// Each half = 128 rows x 64 cols. Swizzle: 16B-chunk s of row r holds global
// chunk s ^ (r&7) (staged via pre-swizzled global source; linear LDS dest).
template <int MODE, int NT>
__global__ __launch_bounds__(512) void gemm8_k(const u16* __restrict__ A,
                                               const u16* __restrict__ B,
                                               const float* __restrict__ alpha,
                                               const float* __restrict__ beta,
                                               void* __restrict__ outp) {
  __shared__ u16 lds[65536];  // 128 KiB
  const int t = threadIdx.x;
  const int w = t >> 6, ln = t & 63;
  const int wr = w >> 2, wc = w & 3;  // wave grid 2M x 4N; wave tile 128x64
  const int lr = ln & 15, lg = ln >> 4;

  // XCD-GROUPED swizzle (R4): each XCD owns 8 bm-panels x all 4 bn.
  const int lid = blockIdx.x;
  const int xcd = lid & 7, idx = lid >> 3;
  const int bm = xcd * 8 + (idx >> 2);  // 0..63
  const int bn = idx & 3;               // 0..3

  const size_t abase = (size_t)(bm * 256) * 1024;
  const size_t bbase = (size_t)(bn * 256) * 2048;
  // staging: thread t covers (row = c*64 + t>>3, chunk = t&7), source chunk
  // pre-swizzled by row&7 so linear LDS dest ends up swizzled.
  const int srow = t >> 3;                            // 0..63
  const int schunk = ((t & 7) ^ ((t >> 3) & 7)) * 8;  // u16 units
  const int wofs = w * 512;                           // per-wave LDS offset per call

  auto stA = [&](int tile, int half) {
    const int reg = (tile & 1) * 32768 + half * 8192;
    const int acol = (tile * 64) & 1023;  // K'=2048 wraps onto A's K=1024
#pragma unroll
    for (int c = 0; c < 2; ++c)
      g2l16(A + abase + (size_t)(half * 128 + c * 64 + srow) * 1024 + acol + schunk,
            lds + reg + c * 4096 + wofs);
  };
  auto stB = [&](int tile, int half) {
    const int reg = (tile & 1) * 32768 + 16384 + half * 8192;
    const int bcol = tile * 64;
#pragma unroll
    for (int c = 0; c < 2; ++c)
      g2l16(B + bbase + (size_t)(half * 128 + c * 64 + srow) * 2048 + bcol + schunk,
            lds + reg + c * 4096 + wofs);
  };

  // prologue: tile0 full, tile1 minus B-h1 (staged at tile0's P1)
  stA(0, 0); stA(0, 1); stB(0, 0); stB(0, 1);
  stA(1, 0); stA(1, 1); stB(1, 0);

  // fragment read constants: chunk xor is lr&7 (row = ..16*mi + lr => row&7 = lr&7)
  const int c0 = ((lg) ^ (lr & 7)) * 8;      // ks=0
  const int c1 = ((4 + lg) ^ (lr & 7)) * 8;  // ks=1

  f32x4 acc[8][4] = {};

  asm volatile("s_waitcnt vmcnt(6)" ::: "memory");  // tile0 ready (tile1's 6 in flight)
  __builtin_amdgcn_s_barrier();

#pragma unroll 1
  for (int tt = 0; tt < NT; ++tt) {
    const int bb0 = (tt & 1) * 32768;
    const u16* Ar = lds + bb0 + wr * 8192;                              // wave's A rows
    const u16* Br = lds + bb0 + 16384 + (wc >> 1) * 8192 + (wc & 1) * 4096;  // wave's B cols
    bf16x8 a0[8], a1[8], b0[4], b1[4];

    // ---- P1 (quad 0,0): read A-l0 (8) + B-n0 (4); stage Bh1(tt+1) ----
#pragma unroll
    for (int mi = 0; mi < 4; ++mi) {
      a0[mi * 2 + 0] = *(const bf16x8*)&Ar[(mi * 16 + lr) * 64 + c0];
      a0[mi * 2 + 1] = *(const bf16x8*)&Ar[(mi * 16 + lr) * 64 + c1];
    }
#pragma unroll
    for (int nj = 0; nj < 2; ++nj) {
      b0[nj * 2 + 0] = *(const bf16x8*)&Br[(nj * 16 + lr) * 64 + c0];
      b0[nj * 2 + 1] = *(const bf16x8*)&Br[(nj * 16 + lr) * 64 + c1];
    }
    if (tt + 1 < NT) stB(tt + 1, 1);
    asm volatile("s_waitcnt lgkmcnt(8)" ::: "memory");  // throttle: 12 reads issued
    __builtin_amdgcn_sched_barrier(0);
    __builtin_amdgcn_s_barrier();
    asm volatile("s_waitcnt lgkmcnt(0)" ::: "memory");
    __builtin_amdgcn_sched_barrier(0);
    __builtin_amdgcn_s_setprio(1);
#pragma unroll
    for (int mi = 0; mi < 4; ++mi)
#pragma unroll
      for (int nj = 0; nj < 2; ++nj) {
        acc[mi][nj] = mfma16(a0[mi * 2 + 0], b0[nj * 2 + 0], acc[mi][nj]);
        acc[mi][nj] = mfma16(a0[mi * 2 + 1], b0[nj * 2 + 1], acc[mi][nj]);
      }
    __builtin_amdgcn_s_setprio(0);
    __builtin_amdgcn_sched_barrier(0);
    __builtin_amdgcn_s_barrier();

    // ---- P2 (quad 1,0): read A-l1 (8); MFMA acc[4..7][0..1] ----
#pragma unroll
    for (int mi = 0; mi < 4; ++mi) {
      a1[mi * 2 + 0] = *(const bf16x8*)&Ar[((mi + 4) * 16 + lr) * 64 + c0];
      a1[mi * 2 + 1] = *(const bf16x8*)&Ar[((mi + 4) * 16 + lr) * 64 + c1];
    }
    __builtin_amdgcn_sched_barrier(0);
    __builtin_amdgcn_s_barrier();
    asm volatile("s_waitcnt lgkmcnt(0)" ::: "memory");
    __builtin_amdgcn_sched_barrier(0);
    __builtin_amdgcn_s_setprio(1);
#pragma unroll
    for (int mi = 0; mi < 4; ++mi)
#pragma unroll
      for (int nj = 0; nj < 2; ++nj) {
        acc[mi + 4][nj] = mfma16(a1[mi * 2 + 0], b0[nj * 2 + 0], acc[mi + 4][nj]);
        acc[mi + 4][nj] = mfma16(a1[mi * 2 + 1], b0[nj * 2 + 1], acc[mi + 4][nj]);
      }
    __builtin_amdgcn_s_setprio(0);
    __builtin_amdgcn_sched_barrier(0);
    __builtin_amdgcn_s_barrier();

    // ---- P3 (quad 1,1): read B-n1 (4); stage Ah0(tt+2); MFMA acc[4..7][2..3] ----
#pragma unroll
    for (int nj = 0; nj < 2; ++nj) {
      b1[nj * 2 + 0] = *(const bf16x8*)&Br[((nj + 2) * 16 + lr) * 64 + c0];
      b1[nj * 2 + 1] = *(const bf16x8*)&Br[((nj + 2) * 16 + lr) * 64 + c1];
    }
    if (tt + 2 < NT) stA(tt + 2, 0);
    __builtin_amdgcn_sched_barrier(0);
    __builtin_amdgcn_s_barrier();
    asm volatile("s_waitcnt lgkmcnt(0)" ::: "memory");
    __builtin_amdgcn_sched_barrier(0);
    __builtin_amdgcn_s_setprio(1);
#pragma unroll
    for (int mi = 0; mi < 4; ++mi)
#pragma unroll
      for (int nj = 0; nj < 2; ++nj) {
        acc[mi + 4][nj + 2] = mfma16(a1[mi * 2 + 0], b1[nj * 2 + 0], acc[mi + 4][nj + 2]);
        acc[mi + 4][nj + 2] = mfma16(a1[mi * 2 + 1], b1[nj * 2 + 1], acc[mi + 4][nj + 2]);
      }
    __builtin_amdgcn_s_setprio(0);
    __builtin_amdgcn_sched_barrier(0);
    __builtin_amdgcn_s_barrier();

    // ---- P4 (quad 0,1): no reads; stage Ah1+Bh0(tt+2); MFMA acc[0..3][2..3]; gate ----
    if (tt + 2 < NT) { stA(tt + 2, 1); stB(tt + 2, 0); }
    __builtin_amdgcn_sched_barrier(0);
    __builtin_amdgcn_s_barrier();
    __builtin_amdgcn_s_setprio(1);
#pragma unroll
    for (int mi = 0; mi < 4; ++mi)
#pragma unroll
      for (int nj = 0; nj < 2; ++nj) {
        acc[mi][nj + 2] = mfma16(a0[mi * 2 + 0], b1[nj * 2 + 0], acc[mi][nj + 2]);
        acc[mi][nj + 2] = mfma16(a0[mi * 2 + 1], b1[nj * 2 + 1], acc[mi][nj + 2]);
      }
    __builtin_amdgcn_s_setprio(0);
    __builtin_amdgcn_sched_barrier(0);
    // counted gate for tile tt+1: younger-than-Bh1(tt+1) = 6 loads (P3+P4 stages)
    if (tt < NT - 2) {
      asm volatile("s_waitcnt vmcnt(6)" ::: "memory");
    } else if (tt == NT - 2) {
      asm volatile("s_waitcnt vmcnt(0)" ::: "memory");
    }
    __builtin_amdgcn_s_barrier();
  }

  // ---- epilogue: val = acc*alpha[n] + beta[n] ----
#pragma unroll
  for (int nj = 0; nj < 4; ++nj) {
    const int gn = bn * 256 + wc * 64 + nj * 16 + lr;
    const float al = alpha[gn], be = beta[gn];
#pragma unroll
    for (int mi = 0; mi < 8; ++mi) {
      const int gm0 = bm * 256 + wr * 128 + mi * 16 + lg * 4;
      if constexpr (MODE == 0) {
        u16* o = (u16*)outp;
#pragma unroll
        for (int r = 0; r < 4; ++r) {
          float v = spikef(acc[mi][nj][r] * al + be);
          o[(size_t)(gm0 + r) * 1024 + gn] = rne_bf16(v);
        }
      } else if constexpr (MODE == 1) {
        u16* o = (u16*)outp;
        const int bi = gm0 >> 12, tok = gm0 & 4095;
        const int hh = gn >> 6, dd = gn & 63;
        us4 pack;
#pragma unroll
        for (int r = 0; r < 4; ++r)
          pack[r] = rne_bf16(spikef(acc[mi][nj][r] * al + be));
        *(us4*)&o[((size_t)((bi * 16 + hh) * 64 + dd)) * 4096 + tok] = pack;
      } else {
        float* o = (float*)outp;
#pragma unroll
        for (int r = 0; r < 4; ++r)
          o[(size_t)(gm0 + r) * 1024 + gn] = acc[mi][nj][r] * al + be;
      }
    }
  }
}

// ---------------- scores = K^T V per (b,h): 64x64, K-dim 4096 in 4 chunks ----------------
__global__ __launch_bounds__(256) void scores_k(const u16* __restrict__ Kt,
                                                const u16* __restrict__ Vt,
                                                float* __restrict__ sc) {
  __shared__ u16 lsA[64 * 64], lsB[64 * 64];
  const int t = threadIdx.x;
  const int bh = blockIdx.y, ck = blockIdx.x;
  const int wv = t >> 6, ln = t & 63;
  const int wm = wv & 1, wn = wv >> 1;
  const int lr = ln & 15, lk = (ln >> 4) << 3, lg = ln >> 4;
  const size_t base = (size_t)bh * 64 * 4096 + (size_t)ck * 1024;
  f32x4 acc[2][2] = {};
  const int srow = t >> 3;        // 0..31
  const int scol = (t & 7) << 3;  // 0..56

  for (int kt = 0; kt < 16; ++kt) {
    __syncthreads();
#pragma unroll
    for (int i = 0; i < 2; ++i) {
      g2l16(Kt + base + (size_t)(i * 32 + srow) * 4096 + kt * 64 + scol,
            lsA + i * 2048 + wv * 512);
      g2l16(Vt + base + (size_t)(i * 32 + srow) * 4096 + kt * 64 + scol,
            lsB + i * 2048 + wv * 512);
    }
    __syncthreads();
#pragma unroll
    for (int ks = 0; ks < 2; ++ks) {
      bf16x8 fa[2], fb[2];
#pragma unroll
      for (int mi = 0; mi < 2; ++mi)
        fa[mi] = *(const bf16x8*)&lsA[(wm * 32 + mi * 16 + lr) * 64 + ks * 32 + lk];
#pragma unroll
      for (int nj = 0; nj < 2; ++nj)
        fb[nj] = *(const bf16x8*)&lsB[(wn * 32 + nj * 16 + lr) * 64 + ks * 32 + lk];
#pragma unroll
      for (int mi = 0; mi < 2; ++mi)
#pragma unroll
        for (int nj = 0; nj < 2; ++nj)
          acc[mi][nj] = mfma16(fa[mi], fb[nj], acc[mi][nj]);
    }
  }
  float* dst = sc + (size_t)bh * 4096;
#pragma unroll
  for (int mi = 0; mi < 2; ++mi)
#pragma unroll
    for (int nj = 0; nj < 2; ++nj)
#pragma unroll
      for (int r = 0; r < 4; ++r) {
        int d = wm * 32 + mi * 16 + lg * 4 + r;
        int e = wn * 32 + nj * 16 + lr;
        atomicAdd(&dst[d * 64 + e], acc[mi][nj][r]);
      }
}

// ---------------- phase B: Xo = spike(0.125 * Q @ scores) per (b,h) ----------------
__global__ __launch_bounds__(256) void phaseB_k(const u16* __restrict__ Qs,
                                                const float* __restrict__ sc,
                                                u16* __restrict__ Xo) {
  __shared__ u16 lsQ[128 * 64];
  __shared__ u16 sTh[64 * 64];
  __shared__ u16 sTl[64 * 64];
  const int t = threadIdx.x;
  const int mc = blockIdx.x, bh = blockIdx.y;
  const int b = bh >> 4, h = bh & 15;

#pragma unroll
  for (int i = 0; i < 16; ++i) {
    int idx = i * 256 + t;
    int dd = idx >> 6, ee = idx & 63;
    float v = sc[(size_t)bh * 4096 + idx];
    int iv = (int)v;  // scores are exact integers
    int hi = iv & ~0xFF;
    sTh[ee * 64 + dd] = rne_bf16((float)hi);
    sTl[ee * 64 + dd] = rne_bf16((float)(iv - hi));
  }

  const int wv = t >> 6, ln = t & 63;
  const size_t qbase = ((size_t)(b * 4096 + mc * 128)) * 1024 + h * 64;
  const int srow = t >> 3, scol = (t & 7) << 3;
#pragma unroll
  for (int i = 0; i < 4; ++i)
    g2l16(Qs + qbase + (size_t)(i * 32 + srow) * 1024 + scol, lsQ + i * 2048 + wv * 512);
  __syncthreads();

  const int lr = ln & 15, lk = (ln >> 4) << 3, lg = ln >> 4;
  f32x4 acc[2][4] = {};
#pragma unroll
  for (int ks = 0; ks < 2; ++ks) {
    bf16x8 fa[2];
#pragma unroll
    for (int mi = 0; mi < 2; ++mi)
      fa[mi] = *(const bf16x8*)&lsQ[(wv * 32 + mi * 16 + lr) * 64 + ks * 32 + lk];
#pragma unroll
    for (int nj = 0; nj < 4; ++nj) {
      bf16x8 fh = *(const bf16x8*)&sTh[(nj * 16 + lr) * 64 + ks * 32 + lk];
      bf16x8 fl = *(const bf16x8*)&sTl[(nj * 16 + lr) * 64 + ks * 32 + lk];
#pragma unroll
      for (int mi = 0; mi < 2; ++mi) {
        acc[mi][nj] = mfma16(fa[mi], fh, acc[mi][nj]);
        acc[mi][nj] = mfma16(fa[mi], fl, acc[mi][nj]);
      }
    }
  }
#pragma unroll
  for (int mi = 0; mi < 2; ++mi)
#pragma unroll
    for (int nj = 0; nj < 4; ++nj)
#pragma unroll
      for (int r = 0; r < 4; ++r) {
        int tok = mc * 128 + wv * 32 + mi * 16 + lg * 4 + r;
        int e = nj * 16 + lr;
        float v = spikef(acc[mi][nj][r] * 0.125f);  // SCALE = 64^-0.5
        Xo[((size_t)(b * 4096 + tok)) * 1024 + h * 64 + e] = rne_bf16(v);
      }
}

// ---------------- host launch ----------------

extern "C" void kernel_launch(void* const* d_in, const int* in_sizes, int n_in,
                              void* d_out, int out_size, void* d_ws, size_t ws_size,
                              hipStream_t stream) {
  (void)in_sizes; (void)n_in; (void)out_size; (void)ws_size;

  const float* xin[3] = {(const float*)d_in[0], (const float*)d_in[1], (const float*)d_in[2]};
  const float* Wf[4] = {(const float*)d_in[3], (const float*)d_in[7],
                        (const float*)d_in[11], (const float*)d_in[15]};
  const float* Bf[4] = {(const float*)d_in[4], (const float*)d_in[8],
                        (const float*)d_in[12], (const float*)d_in[16]};
  const float* Sf[4] = {(const float*)d_in[5], (const float*)d_in[9],
                        (const float*)d_in[13], (const float*)d_in[17]};
  const float* Tf[4] = {(const float*)d_in[6], (const float*)d_in[10],
                        (const float*)d_in[14], (const float*)d_in[18]};

  char* ws = (char*)d_ws;
  const size_t MB = 1ull << 20;
  u16* W2[4];
  for (int i = 0; i < 4; ++i) W2[i] = (u16*)(ws + (size_t)i * 4 * MB);  // 1024x2048 bf16
  float* betas = (float*)(ws + 16 * MB);   // 4 x 1024 f32
  u16* Xbuf = (u16*)(ws + 18 * MB);        // 32MB: quantized input, later Xo
  u16* Qs   = (u16*)(ws + 50 * MB);        // 32MB (B,N,C) bf16
  u16* Ktp  = (u16*)(ws + 82 * MB);        // 32MB (B*H,64,4096) bf16
  u16* Vtp  = (u16*)(ws + 114 * MB);       // 32MB

  float* out0 = (float*)d_out;
  float* scores = out0 + 16777216;  // 4*16*64*64 = 262144 f32

  for (int i = 0; i < 4; ++i) {
    wsplit_k<<<1024, 256, 0, stream>>>((const float4*)Wf[i], W2[i]);
    beta_k<<<4, 256, 0, stream>>>(Bf[i], Sf[i], Tf[i], betas + i * 1024);
  }

  // Q path (hi weights only: downstream saturation masks rounding flips)
  quant_k<<<16384, 256, 0, stream>>>((const float4*)xin[0], (us4*)Xbuf, 4194304);
  gemm8_k<0, 16><<<256, 512, 0, stream>>>(Xbuf, W2[0], Sf[0], betas + 0, Qs);

  // K path (split hi+lo: scores validated directly -> near-f32 precision)
  quant_k<<<16384, 256, 0, stream>>>((const float4*)xin[1], (us4*)Xbuf, 4194304);
  gemm8_k<1, 32><<<256, 512, 0, stream>>>(Xbuf, W2[1], Sf[1], betas + 1024, Ktp);

  // V path (split hi+lo)
  quant_k<<<16384, 256, 0, stream>>>((const float4*)xin[2], (us4*)Xbuf, 4194304);
  gemm8_k<1, 32><<<256, 512, 0, stream>>>(Xbuf, W2[2], Sf[2], betas + 2048, Vtp);

  // scores (exact integers, deterministic atomics)
  hipMemsetAsync(scores, 0, 262144 * sizeof(float), stream);
  scores_k<<<dim3(4, 64), 256, 0, stream>>>(Ktp, Vtp, scores);

  // out = spike(Q @ scores * 0.125) -> Xbuf (reused as Xo)
  phaseB_k<<<dim3(32, 64), 256, 0, stream>>>(Qs, scores, Xbuf);

  // final conv_bn -> f32 d_out
  gemm8_k<2, 16><<<256, 512, 0, stream>>>(Xbuf, W2[3], Sf[3], betas + 3072, (void*)out0);
}

// Round 6
// 318.981 us; speedup vs baseline: 1.2912x; 1.0770x over previous
//
#include <hip/hip_runtime.h>

// MSMultiHeadAttentionBlock (MI355X gfx950). B=4,N=4096,C=1024,H=16,D=64.
// R6: (1) de-pinned bf16 split GEMM (no lgkmcnt asm / sched_barrier pins;
//     barriers + counted vmcnt gates + setprio only);
//     (2) Q-GEMM in i8 (mfma_i32_16x16x64_i8, w1=round(W*1024));
//     (3) K/V spike outputs + scores in i8 (exact);
//     (4) fused prep/quant launches.

typedef __attribute__((ext_vector_type(8))) short bf16x8;
typedef __attribute__((ext_vector_type(4))) float f32x4;
typedef __attribute__((ext_vector_type(4))) int i32x4;
typedef __attribute__((ext_vector_type(4))) unsigned short us4;
typedef unsigned short u16;
typedef unsigned int u32;
typedef unsigned char u8;

__device__ __forceinline__ u16 rne_bf16(float f) {
  u32 u = __float_as_uint(f);
  u += 0x7FFFu + ((u >> 16) & 1u);
  return (u16)(u >> 16);
}
__device__ __forceinline__ float bf16f(u16 h) { return __uint_as_float(((u32)h) << 16); }
// round-half-even(clamp(x,0,4)) — rintf is RNE, matches jnp.round
__device__ __forceinline__ float spikef(float v) { return rintf(fminf(fmaxf(v, 0.f), 4.f)); }

__device__ __forceinline__ void g2l16(const void* g, void* l) {
  __builtin_amdgcn_global_load_lds((const __attribute__((address_space(1))) void*)g,
                                   (__attribute__((address_space(3))) void*)l, 16, 0, 0);
}
__device__ __forceinline__ f32x4 mfma16(bf16x8 a, bf16x8 b, f32x4 c) {
  return __builtin_amdgcn_mfma_f32_16x16x32_bf16(a, b, c, 0, 0, 0);
}
__device__ __forceinline__ i32x4 mfma8i(i32x4 a, i32x4 b, i32x4 c) {
  return __builtin_amdgcn_mfma_i32_16x16x64_i8(a, b, c, 0, 0, 0);
}

// ---------------- prep: weights + fused beta ----------------
// blocks 0..1023: weight convert; block 1024: beta = b*s+t
__global__ __launch_bounds__(256) void prep_bf_k(const float4* __restrict__ w,
                                                 u16* __restrict__ W2,
                                                 const float* __restrict__ b,
                                                 const float* __restrict__ s,
                                                 const float* __restrict__ t,
                                                 float* __restrict__ beta) {
  if (blockIdx.x == 1024) {
    for (int j = threadIdx.x; j < 1024; j += 256) beta[j] = b[j] * s[j] + t[j];
    return;
  }
  int i = blockIdx.x * 256 + threadIdx.x;  // float4 idx
  float4 v = w[i];
  int flat = i * 4, n = flat >> 10, c = flat & 1023;
  float cc[4] = {v.x, v.y, v.z, v.w};
  us4 h, l;
#pragma unroll
  for (int j = 0; j < 4; ++j) {
    u16 hb = rne_bf16(cc[j]);
    h[j] = hb;
    l[j] = rne_bf16(cc[j] - bf16f(hb));
  }
  *(us4*)&W2[(size_t)n * 2048 + c] = h;
  *(us4*)&W2[(size_t)n * 2048 + 1024 + c] = l;
}

__global__ __launch_bounds__(256) void prep_i8_k(const float4* __restrict__ w,
                                                 u8* __restrict__ W1,
                                                 const float* __restrict__ b,
                                                 const float* __restrict__ s,
                                                 const float* __restrict__ t,
                                                 float* __restrict__ beta) {
  if (blockIdx.x == 1024) {
    for (int j = threadIdx.x; j < 1024; j += 256) beta[j] = b[j] * s[j] + t[j];
    return;
  }
  int i = blockIdx.x * 256 + threadIdx.x;
  float4 v = w[i];
  float cc[4] = {v.x, v.y, v.z, v.w};
  u32 pack = 0;
#pragma unroll
  for (int j = 0; j < 4; ++j) {
    int x = (int)rintf(cc[j] * 1024.f);
    x = x > 127 ? 127 : (x < -127 ? -127 : x);
    pack |= ((u32)(u8)(char)x) << (8 * j);
  }
  *(u32*)&W1[(size_t)i * 4] = pack;
}

// ---------------- quant: q->i8, k->bf16 (fused); v->bf16 ----------------
__global__ __launch_bounds__(256) void quant2_k(const float4* __restrict__ q,
                                                const float4* __restrict__ k,
                                                u8* __restrict__ qo,
                                                u16* __restrict__ ko) {
  int i = blockIdx.x * 256 + threadIdx.x;
  if (blockIdx.y == 0) {
    float4 v = q[i];
    float cc[4] = {v.x, v.y, v.z, v.w};
    u32 pack = 0;
#pragma unroll
    for (int j = 0; j < 4; ++j) pack |= ((u32)(int)spikef(cc[j])) << (8 * j);
    *(u32*)&qo[(size_t)i * 4] = pack;
  } else {
    float4 v = k[i];
    us4 o;
    o[0] = rne_bf16(spikef(v.x));
    o[1] = rne_bf16(spikef(v.y));
    o[2] = rne_bf16(spikef(v.z));
    o[3] = rne_bf16(spikef(v.w));
    *(us4*)&ko[(size_t)i * 4] = o;
  }
}

__global__ __launch_bounds__(256) void quantv_k(const float4* __restrict__ in,
                                                u16* __restrict__ out) {
  int i = blockIdx.x * 256 + threadIdx.x;
  float4 v = in[i];
  us4 o;
  o[0] = rne_bf16(spikef(v.x));
  o[1] = rne_bf16(spikef(v.y));
  o[2] = rne_bf16(spikef(v.z));
  o[3] = rne_bf16(spikef(v.w));
  *(us4*)&out[(size_t)i * 4] = o;
}

// ---------------- bf16 split GEMM, de-pinned 4-phase (K/V, O) ----------------
// MODE 1: spike -> i8 transposed (B,H,D,N); MODE 2: f32 natural (O -> d_out)
template <int MODE, int NT>
__global__ __launch_bounds__(512) void gemm8_k(const u16* __restrict__ A,
                                               const u16* __restrict__ B,
                                               const float* __restrict__ alpha,
                                               const float* __restrict__ beta,
                                               void* __restrict__ outp) {
  __shared__ u16 lds[65536];
  const int t = threadIdx.x;
  const int w = t >> 6, ln = t & 63;
  const int wr = w >> 2, wc = w & 3;
  const int lr = ln & 15, lg = ln >> 4;

  const int lid = blockIdx.x;
  const int xcd = lid & 7, idx = lid >> 3;
  const int bm = xcd * 8 + (idx >> 2);
  const int bn = idx & 3;

  const size_t abase = (size_t)(bm * 256) * 1024;
  const size_t bbase = (size_t)(bn * 256) * 2048;
  const int srow = t >> 3;
  const int schunk = ((t & 7) ^ ((t >> 3) & 7)) * 8;
  const int wofs = w * 512;

  auto stA = [&](int tile, int half) {
    const int reg = (tile & 1) * 32768 + half * 8192;
    const int acol = (tile * 64) & 1023;
#pragma unroll
    for (int c = 0; c < 2; ++c)
      g2l16(A + abase + (size_t)(half * 128 + c * 64 + srow) * 1024 + acol + schunk,
            lds + reg + c * 4096 + wofs);
  };
  auto stB = [&](int tile, int half) {
    const int reg = (tile & 1) * 32768 + 16384 + half * 8192;
    const int bcol = tile * 64;
#pragma unroll
    for (int c = 0; c < 2; ++c)
      g2l16(B + bbase + (size_t)(half * 128 + c * 64 + srow) * 2048 + bcol + schunk,
            lds + reg + c * 4096 + wofs);
  };

  stA(0, 0); stA(0, 1); stB(0, 0); stB(0, 1);
  stA(1, 0); stA(1, 1); stB(1, 0);

  const int c0 = ((lg) ^ (lr & 7)) * 8;
  const int c1 = ((4 + lg) ^ (lr & 7)) * 8;

  f32x4 acc[8][4] = {};

  asm volatile("s_waitcnt vmcnt(6)" ::: "memory");
  __builtin_amdgcn_s_barrier();

#pragma unroll 1
  for (int tt = 0; tt < NT; ++tt) {
    const int bb0 = (tt & 1) * 32768;
    const u16* Ar = lds + bb0 + wr * 8192;
    const u16* Br = lds + bb0 + 16384 + (wc >> 1) * 8192 + (wc & 1) * 4096;
    bf16x8 a0[8], a1[8], b0[4], b1[4];

    // P1: reads a0+b0, stage Bh1(tt+1), MFMA quad(0..3, 0..1)
#pragma unroll
    for (int mi = 0; mi < 4; ++mi) {
      a0[mi * 2 + 0] = *(const bf16x8*)&Ar[(mi * 16 + lr) * 64 + c0];
      a0[mi * 2 + 1] = *(const bf16x8*)&Ar[(mi * 16 + lr) * 64 + c1];
    }
#pragma unroll
    for (int nj = 0; nj < 2; ++nj) {
      b0[nj * 2 + 0] = *(const bf16x8*)&Br[(nj * 16 + lr) * 64 + c0];
      b0[nj * 2 + 1] = *(const bf16x8*)&Br[(nj * 16 + lr) * 64 + c1];
    }
    if (tt + 1 < NT) stB(tt + 1, 1);
    __builtin_amdgcn_s_barrier();
    __builtin_amdgcn_s_setprio(1);
#pragma unroll
    for (int mi = 0; mi < 4; ++mi)
#pragma unroll
      for (int nj = 0; nj < 2; ++nj) {
        acc[mi][nj] = mfma16(a0[mi * 2 + 0], b0[nj * 2 + 0], acc[mi][nj]);
        acc[mi][nj] = mfma16(a0[mi * 2 + 1], b0[nj * 2 + 1], acc[mi][nj]);
      }
    __builtin_amdgcn_s_setprio(0);
    __builtin_amdgcn_s_barrier();

    // P2: reads a1, MFMA quad(4..7, 0..1)
#pragma unroll
    for (int mi = 0; mi < 4; ++mi) {
      a1[mi * 2 + 0] = *(const bf16x8*)&Ar[((mi + 4) * 16 + lr) * 64 + c0];
      a1[mi * 2 + 1] = *(const bf16x8*)&Ar[((mi + 4) * 16 + lr) * 64 + c1];
    }
    __builtin_amdgcn_s_barrier();
    __builtin_amdgcn_s_setprio(1);
#pragma unroll
    for (int mi = 0; mi < 4; ++mi)
#pragma unroll
      for (int nj = 0; nj < 2; ++nj) {
        acc[mi + 4][nj] = mfma16(a1[mi * 2 + 0], b0[nj * 2 + 0], acc[mi + 4][nj]);
        acc[mi + 4][nj] = mfma16(a1[mi * 2 + 1], b0[nj * 2 + 1], acc[mi + 4][nj]);
      }
    __builtin_amdgcn_s_setprio(0);
    __builtin_amdgcn_s_barrier();

    // P3: reads b1, stage Ah0(tt+2), MFMA quad(4..7, 2..3)
#pragma unroll
    for (int nj = 0; nj < 2; ++nj) {
      b1[nj * 2 + 0] = *(const bf16x8*)&Br[((nj + 2) * 16 + lr) * 64 + c0];
      b1[nj * 2 + 1] = *(const bf16x8*)&Br[((nj + 2) * 16 + lr) * 64 + c1];
    }
    if (tt + 2 < NT) stA(tt + 2, 0);
    __builtin_amdgcn_s_barrier();
    __builtin_amdgcn_s_setprio(1);
#pragma unroll
    for (int mi = 0; mi < 4; ++mi)
#pragma unroll
      for (int nj = 0; nj < 2; ++nj) {
        acc[mi + 4][nj + 2] = mfma16(a1[mi * 2 + 0], b1[nj * 2 + 0], acc[mi + 4][nj + 2]);
        acc[mi + 4][nj + 2] = mfma16(a1[mi * 2 + 1], b1[nj * 2 + 1], acc[mi + 4][nj + 2]);
      }
    __builtin_amdgcn_s_setprio(0);
    __builtin_amdgcn_s_barrier();

    // P4: stage Ah1+Bh0(tt+2), MFMA quad(0..3, 2..3), gate
    if (tt + 2 < NT) { stA(tt + 2, 1); stB(tt + 2, 0); }
    __builtin_amdgcn_s_barrier();
    __builtin_amdgcn_s_setprio(1);
#pragma unroll
    for (int mi = 0; mi < 4; ++mi)
#pragma unroll
      for (int nj = 0; nj < 2; ++nj) {
        acc[mi][nj + 2] = mfma16(a0[mi * 2 + 0], b1[nj * 2 + 0], acc[mi][nj + 2]);
        acc[mi][nj + 2] = mfma16(a0[mi * 2 + 1], b1[nj * 2 + 1], acc[mi][nj + 2]);
      }
    __builtin_amdgcn_s_setprio(0);
    if (tt < NT - 2) {
      asm volatile("s_waitcnt vmcnt(6)" ::: "memory");
    } else if (tt == NT - 2) {
      asm volatile("s_waitcnt vmcnt(0)" ::: "memory");
    }
    __builtin_amdgcn_s_barrier();
  }

  // epilogue
#pragma unroll
  for (int nj = 0; nj < 4; ++nj) {
    const int gn = bn * 256 + wc * 64 + nj * 16 + lr;
    const float al = alpha[gn], be = beta[gn];
#pragma unroll
    for (int mi = 0; mi < 8; ++mi) {
      const int gm0 = bm * 256 + wr * 128 + mi * 16 + lg * 4;
      if constexpr (MODE == 1) {
        u8* o = (u8*)outp;
        const int bi = gm0 >> 12, tok = gm0 & 4095;
        const int hh = gn >> 6, dd = gn & 63;
        u32 pack = 0;
#pragma unroll
        for (int r = 0; r < 4; ++r)
          pack |= ((u32)(int)spikef(acc[mi][nj][r] * al + be)) << (8 * r);
        *(u32*)&o[((size_t)((bi * 16 + hh) * 64 + dd)) * 4096 + tok] = pack;
      } else {
        float* o = (float*)outp;
#pragma unroll
        for (int r = 0; r < 4; ++r)
          o[(size_t)(gm0 + r) * 1024 + gn] = acc[mi][nj][r] * al + be;
      }
    }
  }
}

// ---------------- i8 GEMM for Q: C = A(i8 {0..4}) x W1^T, K=1024 ----------------
// epilogue: spike(acc * s/1024 + beta) -> bf16 natural (B,N,C)
__global__ __launch_bounds__(512) void gemm_q_k(const u8* __restrict__ A,
                                                const u8* __restrict__ B,
                                                const float* __restrict__ alpha,
                                                const float* __restrict__ beta,
                                                u16* __restrict__ outp) {
  constexpr int NT = 16;
  __shared__ u8 lds[65536];  // 2 bufs x (A 16KB + B 16KB)
  const int t = threadIdx.x;
  const int w = t >> 6, ln = t & 63;
  const int wr = w >> 2, wc = w & 3;
  const int lr = ln & 15, lg = ln >> 4;

  const int lid = blockIdx.x;
  const int xcd = lid & 7, idx = lid >> 3;
  const int bm = xcd * 8 + (idx >> 2);
  const int bn = idx & 3;

  const size_t abase = (size_t)(bm * 256) * 1024;
  const size_t bbase = (size_t)(bn * 256) * 1024;
  const int srow = t >> 2;                             // 0..127 rows per half
  const int schunk = ((t & 3) ^ ((t >> 3) & 3)) * 16;  // bytes
  // one g2l16 per thread covers an 8KB half; dest wave-uniform base:
  const int wofs = w * 1024;

  auto stA = [&](int tile, int half) {
    const int reg = (tile & 1) * 32768 + half * 8192;
    g2l16(A + abase + (size_t)(half * 128 + srow) * 1024 + tile * 64 + schunk,
          lds + reg + wofs);
  };
  auto stB = [&](int tile, int half) {
    const int reg = (tile & 1) * 32768 + 16384 + half * 8192;
    g2l16(B + bbase + (size_t)(half * 128 + srow) * 1024 + tile * 64 + schunk,
          lds + reg + wofs);
  };

  stA(0, 0); stA(0, 1); stB(0, 0); stB(0, 1);
  stA(1, 0); stA(1, 1); stB(1, 0);

  const int ch = (lg ^ ((lr >> 1) & 3)) * 16;  // swizzled 16B chunk
  i32x4 acc[8][4] = {};

  asm volatile("s_waitcnt vmcnt(3)" ::: "memory");
  __builtin_amdgcn_s_barrier();

#pragma unroll 1
  for (int tt = 0; tt < NT; ++tt) {
    const int bb0 = (tt & 1) * 32768;
    const u8* Ar = lds + bb0 + wr * 8192;
    const u8* Br = lds + bb0 + 16384 + (wc >> 1) * 8192 + (wc & 1) * 4096;
    i32x4 a0[4], a1[4], b0[2], b1[2];

    // P1
#pragma unroll
    for (int mi = 0; mi < 4; ++mi) a0[mi] = *(const i32x4*)&Ar[(mi * 16 + lr) * 64 + ch];
#pragma unroll
    for (int nj = 0; nj < 2; ++nj) b0[nj] = *(const i32x4*)&Br[(nj * 16 + lr) * 64 + ch];
    if (tt + 1 < NT) stB(tt + 1, 1);
    __builtin_amdgcn_s_barrier();
    __builtin_amdgcn_s_setprio(1);
#pragma unroll
    for (int mi = 0; mi < 4; ++mi)
#pragma unroll
      for (int nj = 0; nj < 2; ++nj) acc[mi][nj] = mfma8i(a0[mi], b0[nj], acc[mi][nj]);
    __builtin_amdgcn_s_setprio(0);
    __builtin_amdgcn_s_barrier();

    // P2
#pragma unroll
    for (int mi = 0; mi < 4; ++mi)
      a1[mi] = *(const i32x4*)&Ar[((mi + 4) * 16 + lr) * 64 + ch];
    __builtin_amdgcn_s_barrier();
    __builtin_amdgcn_s_setprio(1);
#pragma unroll
    for (int mi = 0; mi < 4; ++mi)
#pragma unroll
      for (int nj = 0; nj < 2; ++nj)
        acc[mi + 4][nj] = mfma8i(a1[mi], b0[nj], acc[mi + 4][nj]);
    __builtin_amdgcn_s_setprio(0);
    __builtin_amdgcn_s_barrier();

    // P3
#pragma unroll
    for (int nj = 0; nj < 2; ++nj)
      b1[nj] = *(const i32x4*)&Br[((nj + 2) * 16 + lr) * 64 + ch];
    if (tt + 2 < NT) stA(tt + 2, 0);
    __builtin_amdgcn_s_barrier();
    __builtin_amdgcn_s_setprio(1);
#pragma unroll
    for (int mi = 0; mi < 4; ++mi)
#pragma unroll
      for (int nj = 0; nj < 2; ++nj)
        acc[mi + 4][nj + 2] = mfma8i(a1[mi], b1[nj], acc[mi + 4][nj + 2]);
    __builtin_amdgcn_s_setprio(0);
    __builtin_amdgcn_s_barrier();

    // P4
    if (tt + 2 < NT) { stA(tt + 2, 1); stB(tt + 2, 0); }
    __builtin_amdgcn_s_barrier();
    __builtin_amdgcn_s_setprio(1);
#pragma unroll
    for (int mi = 0; mi < 4; ++mi)
#pragma unroll
      for (int nj = 0; nj < 2; ++nj)
        acc[mi][nj + 2] = mfma8i(a0[mi], b1[nj], acc[mi][nj + 2]);
    __builtin_amdgcn_s_setprio(0);
    if (tt < NT - 2) {
      asm volatile("s_waitcnt vmcnt(3)" ::: "memory");
    } else if (tt == NT - 2) {
      asm volatile("s_waitcnt vmcnt(0)" ::: "memory");
    }
    __builtin_amdgcn_s_barrier();
  }

#pragma unroll
  for (int nj = 0; nj < 4; ++nj) {
    const int gn = bn * 256 + wc * 64 + nj * 16 + lr;
    const float al = alpha[gn] * (1.f / 1024.f), be = beta[gn];
#pragma unroll
    for (int mi = 0; mi < 8; ++mi) {
      const int gm0 = bm * 256 + wr * 128 + mi * 16 + lg * 4;
#pragma unroll
      for (int r = 0; r < 4; ++r) {
        float v = spikef((float)acc[mi][nj][r] * al + be);
        outp[(size_t)(gm0 + r) * 1024 + gn] = rne_bf16(v);
      }
    }
  }
}

// ---------------- scores = K^T V (i8, exact), per (b,h) 64x64 ----------------
__global__ __launch_bounds__(256) void scores_k(const u8* __restrict__ Kt,
                                                const u8* __restrict__ Vt,
                                                float* __restrict__ sc) {
  __shared__ u8 lsA[4096], lsB[4096];
  const int t = threadIdx.x;
  const int bh = blockIdx.y, ck = blockIdx.x;
  const int wv = t >> 6, ln = t & 63;
  const int wm = wv & 1, wn = wv >> 1;
  const int lr = ln & 15, lg = ln >> 4;
  const size_t base = (size_t)bh * 262144 + (size_t)ck * 1024;
  i32x4 acc[2][2] = {};
  const int srow = t >> 2;                             // 0..63
  const int schunk = ((t & 3) ^ ((t >> 3) & 3)) * 16;  // bytes
  const int wofs = wv * 1024;
  const int ch = (lg ^ ((lr >> 1) & 3)) * 16;

  for (int kt = 0; kt < 16; ++kt) {
    __syncthreads();
    g2l16(Kt + base + (size_t)srow * 4096 + kt * 64 + schunk, lsA + wofs);
    g2l16(Vt + base + (size_t)srow * 4096 + kt * 64 + schunk, lsB + wofs);
    __syncthreads();
    i32x4 fa[2], fb[2];
#pragma unroll
    for (int mi = 0; mi < 2; ++mi)
      fa[mi] = *(const i32x4*)&lsA[(wm * 32 + mi * 16 + lr) * 64 + ch];
#pragma unroll
    for (int nj = 0; nj < 2; ++nj)
      fb[nj] = *(const i32x4*)&lsB[(wn * 32 + nj * 16 + lr) * 64 + ch];
#pragma unroll
    for (int mi = 0; mi < 2; ++mi)
#pragma unroll
      for (int nj = 0; nj < 2; ++nj) acc[mi][nj] = mfma8i(fa[mi], fb[nj], acc[mi][nj]);
  }
  float* dst = sc + (size_t)bh * 4096;
#pragma unroll
  for (int mi = 0; mi < 2; ++mi)
#pragma unroll
    for (int nj = 0; nj < 2; ++nj)
#pragma unroll
      for (int r = 0; r < 4; ++r) {
        int d = wm * 32 + mi * 16 + lg * 4 + r;
        int e = wn * 32 + nj * 16 + lr;
        atomicAdd(&dst[d * 64 + e], (float)acc[mi][nj][r]);
      }
}

// ---------------- phase B: Xo = spike(0.125 * Q @ scores) ----------------
__global__ __launch_bounds__(256) void phaseB_k(const u16* __restrict__ Qs,
                                                const float* __restrict__ sc,
                                                u16* __restrict__ Xo) {
  __shared__ u16 lsQ[128 * 64];
  __shared__ u16 sTh[64 * 64];
  __shared__ u16 sTl[64 * 64];
  const int t = threadIdx.x;
  const int mc = blockIdx.x, bh = blockIdx.y;
  const int b = bh >> 4, h = bh & 15;

#pragma unroll
  for (int i = 0; i < 16; ++i) {
    int idx = i * 256 + t;
    int dd = idx >> 6, ee = idx & 63;
    float v = sc[(size_t)bh * 4096 + idx];
    int iv = (int)v;
    int hi = iv & ~0xFF;
    sTh[ee * 64 + dd] = rne_bf16((float)hi);
    sTl[ee * 64 + dd] = rne_bf16((float)(iv - hi));
  }

  const int wv = t >> 6, ln = t & 63;
  const size_t qbase = ((size_t)(b * 4096 + mc * 128)) * 1024 + h * 64;
  const int srow = t >> 3, scol = (t & 7) << 3;
#pragma unroll
  for (int i = 0; i < 4; ++i)
    g2l16(Qs + qbase + (size_t)(i * 32 + srow) * 1024 + scol, lsQ + i * 2048 + wv * 512);
  __syncthreads();

  const int lr = ln & 15, lk = (ln >> 4) << 3, lg = ln >> 4;
  f32x4 acc[2][4] = {};
#pragma unroll
  for (int ks = 0; ks < 2; ++ks) {
    bf16x8 fa[2];
#pragma unroll
    for (int mi = 0; mi < 2; ++mi)
      fa[mi] = *(const bf16x8*)&lsQ[(wv * 32 + mi * 16 + lr) * 64 + ks * 32 + lk];
#pragma unroll
    for (int nj = 0; nj < 4; ++nj) {
      bf16x8 fh = *(const bf16x8*)&sTh[(nj * 16 + lr) * 64 + ks * 32 + lk];
      bf16x8 fl = *(const bf16x8*)&sTl[(nj * 16 + lr) * 64 + ks * 32 + lk];
#pragma unroll
      for (int mi = 0; mi < 2; ++mi) {
        acc[mi][nj] = mfma16(fa[mi], fh, acc[mi][nj]);
        acc[mi][nj] = mfma16(fa[mi], fl, acc[mi][nj]);
      }
    }
  }
#pragma unroll
  for (int mi = 0; mi < 2; ++mi)
#pragma unroll
    for (int nj = 0; nj < 4; ++nj)
#pragma unroll
      for (int r = 0; r < 4; ++r) {
        int tok = mc * 128 + wv * 32 + mi * 16 + lg * 4 + r;
        int e = nj * 16 + lr;
        float v = spikef(acc[mi][nj][r] * 0.125f);
        Xo[((size_t)(b * 4096 + tok)) * 1024 + h * 64 + e] = rne_bf16(v);
      }
}

// ---------------- host launch ----------------

extern "C" void kernel_launch(void* const* d_in, const int* in_sizes, int n_in,
                              void* d_out, int out_size, void* d_ws, size_t ws_size,
                              hipStream_t stream) {
  (void)in_sizes; (void)n_in; (void)out_size; (void)ws_size;

  const float* xin[3] = {(const float*)d_in[0], (const float*)d_in[1], (const float*)d_in[2]};
  const float* Wf[4] = {(const float*)d_in[3], (const float*)d_in[7],
                        (const float*)d_in[11], (const float*)d_in[15]};
  const float* Bf[4] = {(const float*)d_in[4], (const float*)d_in[8],
                        (const float*)d_in[12], (const float*)d_in[16]};
  const float* Sf[4] = {(const float*)d_in[5], (const float*)d_in[9],
                        (const float*)d_in[13], (const float*)d_in[17]};
  const float* Tf[4] = {(const float*)d_in[6], (const float*)d_in[10],
                        (const float*)d_in[14], (const float*)d_in[18]};

  char* ws = (char*)d_ws;
  const size_t MB = 1ull << 20;
  u16* W2k = (u16*)(ws + 0 * MB);     // 4MB (1024x2048 bf16)
  u16* W2v = (u16*)(ws + 4 * MB);     // 4MB
  u16* W2o = (u16*)(ws + 8 * MB);     // 4MB
  u8* W1q = (u8*)(ws + 12 * MB);      // 1MB (1024x1024 i8)
  float* betas = (float*)(ws + 13 * MB);  // 4x1024 f32
  u8* q8 = (u8*)(ws + 14 * MB);       // 16MB (B,N,C) i8
  u16* kvbf = (u16*)(ws + 30 * MB);   // 32MB (B,N,C) bf16 (k, then v, then Xo)
  u16* Qs = (u16*)(ws + 62 * MB);     // 32MB (B,N,C) bf16
  u8* Ktp = (u8*)(ws + 94 * MB);      // 16MB (B*H,64,4096) i8
  u8* Vtp = (u8*)(ws + 110 * MB);     // 16MB

  float* out0 = (float*)d_out;
  float* scores = out0 + 16777216;

  // prep (weights + betas)
  prep_i8_k<<<1025, 256, 0, stream>>>((const float4*)Wf[0], W1q, Bf[0], Sf[0], Tf[0], betas);
  prep_bf_k<<<1025, 256, 0, stream>>>((const float4*)Wf[1], W2k, Bf[1], Sf[1], Tf[1],
                                      betas + 1024);
  prep_bf_k<<<1025, 256, 0, stream>>>((const float4*)Wf[2], W2v, Bf[2], Sf[2], Tf[2],
                                      betas + 2048);
  prep_bf_k<<<1025, 256, 0, stream>>>((const float4*)Wf[3], W2o, Bf[3], Sf[3], Tf[3],
                                      betas + 3072);

  // quant q (i8) + k (bf16)
  quant2_k<<<dim3(16384, 2), 256, 0, stream>>>((const float4*)xin[0], (const float4*)xin[1],
                                               q8, kvbf);
  // Q GEMM (i8)
  gemm_q_k<<<256, 512, 0, stream>>>(q8, W1q, Sf[0], betas, Qs);
  // K GEMM (split bf16) -> Ktp i8
  gemm8_k<1, 32><<<256, 512, 0, stream>>>(kvbf, W2k, Sf[1], betas + 1024, Ktp);
  // quant v, V GEMM -> Vtp i8
  quantv_k<<<16384, 256, 0, stream>>>((const float4*)xin[2], kvbf);
  gemm8_k<1, 32><<<256, 512, 0, stream>>>(kvbf, W2v, Sf[2], betas + 2048, Vtp);

  // scores (exact ints, deterministic)
  hipMemsetAsync(scores, 0, 262144 * sizeof(float), stream);
  scores_k<<<dim3(4, 64), 256, 0, stream>>>(Ktp, Vtp, scores);

  // phase B -> Xo (reuse kvbf)
  phaseB_k<<<dim3(32, 64), 256, 0, stream>>>(Qs, scores, kvbf);

  // final conv_bn -> f32 d_out
  gemm8_k<2, 16><<<256, 512, 0, stream>>>(kvbf, W2o, Sf[3], betas + 3072, (void*)out0);
}

// Round 7
// 230.726 us; speedup vs baseline: 1.7851x; 1.3825x over previous
//
#include <hip/hip_runtime.h>

// MSMultiHeadAttentionBlock (MI355X gfx950). B=4,N=4096,C=1024,H=16,D=64.
// R7: ALL GEMMs in i8 MFMA (mfma_i32_16x16x64_i8).
//  - K/V: i8-PAIR weights w=round(W*2^17)=whi*256+wlo (exact split), dual i32 acc.
//  - Q/O: single i8 weights round(W*1024).
//  - phaseB: i8 (scores split exactly into i8 hi/lo), Qs i8.
//  - GEMM tile 256x128, 8 waves (4x2), wave tile 64x64, 4-phase, counted vmcnt
//    gates (3 pair / 2 single), setprio, R6-validated LDS swizzle, XCD-grouped.

typedef __attribute__((ext_vector_type(4))) int i32x4;
typedef unsigned short u16;
typedef unsigned int u32;
typedef unsigned char u8;

// round-half-even(clamp(x,0,4)) — rintf is RNE, matches jnp.round
__device__ __forceinline__ float spikef(float v) { return rintf(fminf(fmaxf(v, 0.f), 4.f)); }

__device__ __forceinline__ void g2l16(const void* g, void* l) {
  // async global->LDS, 16B/lane; LDS dest = wave-uniform base + lane*16
  __builtin_amdgcn_global_load_lds((const __attribute__((address_space(1))) void*)g,
                                   (__attribute__((address_space(3))) void*)l, 16, 0, 0);
}
__device__ __forceinline__ i32x4 mfma8i(i32x4 a, i32x4 b, i32x4 c) {
  return __builtin_amdgcn_mfma_i32_16x16x64_i8(a, b, c, 0, 0, 0);
}

// ---------------- prep: weights + fused beta ----------------
// blocks 0..1023: weight convert; block 1024: beta = b*s+t

// single i8: W1[n][k] = clamp(round(w*1024), +-127)
__global__ __launch_bounds__(256) void prep_i8_k(const float4* __restrict__ w,
                                                 char* __restrict__ W1,
                                                 const float* __restrict__ b,
                                                 const float* __restrict__ s,
                                                 const float* __restrict__ t,
                                                 float* __restrict__ beta) {
  if (blockIdx.x == 1024) {
    for (int j = threadIdx.x; j < 1024; j += 256) beta[j] = b[j] * s[j] + t[j];
    return;
  }
  int i = blockIdx.x * 256 + threadIdx.x;
  float4 v = w[i];
  float cc[4] = {v.x, v.y, v.z, v.w};
  u32 pack = 0;
#pragma unroll
  for (int j = 0; j < 4; ++j) {
    int x = (int)rintf(cc[j] * 1024.f);
    x = x > 127 ? 127 : (x < -127 ? -127 : x);
    pack |= ((u32)(u8)(char)x) << (8 * j);
  }
  *(u32*)&W1[(size_t)i * 4] = pack;
}

// pair i8: w_int = round(w*131072) = whi*256 + wlo, wlo in [-128,127]
// W2[n][k] = whi, W2[n][1024+k] = wlo  (row stride 2048)
__global__ __launch_bounds__(256) void prep_pair_k(const float4* __restrict__ w,
                                                   char* __restrict__ W2,
                                                   const float* __restrict__ b,
                                                   const float* __restrict__ s,
                                                   const float* __restrict__ t,
                                                   float* __restrict__ beta) {
  if (blockIdx.x == 1024) {
    for (int j = threadIdx.x; j < 1024; j += 256) beta[j] = b[j] * s[j] + t[j];
    return;
  }
  int i = blockIdx.x * 256 + threadIdx.x;
  float4 v = w[i];
  int flat = i * 4, n = flat >> 10, c = flat & 1023;
  float cc[4] = {v.x, v.y, v.z, v.w};
  u32 ph = 0, pl = 0;
#pragma unroll
  for (int j = 0; j < 4; ++j) {
    int wi = (int)rintf(cc[j] * 131072.f);
    int lo = ((wi + 128) & 255) - 128;
    int hi = (wi - lo) >> 8;
    hi = hi > 127 ? 127 : (hi < -127 ? -127 : hi);
    ph |= ((u32)(u8)(char)hi) << (8 * j);
    pl |= ((u32)(u8)(char)lo) << (8 * j);
  }
  *(u32*)&W2[(size_t)n * 2048 + c] = ph;
  *(u32*)&W2[(size_t)n * 2048 + 1024 + c] = pl;
}

// ---------------- quant: q/k/v f32 -> spike -> i8 ----------------
__global__ __launch_bounds__(256) void quant3_k(const float4* __restrict__ q,
                                                const float4* __restrict__ k,
                                                const float4* __restrict__ v,
                                                u8* __restrict__ qo, u8* __restrict__ ko,
                                                u8* __restrict__ vo) {
  int i = blockIdx.x * 256 + threadIdx.x;
  const float4* src = blockIdx.y == 0 ? q : (blockIdx.y == 1 ? k : v);
  u8* dst = blockIdx.y == 0 ? qo : (blockIdx.y == 1 ? ko : vo);
  float4 x = src[i];
  float cc[4] = {x.x, x.y, x.z, x.w};
  u32 pack = 0;
#pragma unroll
  for (int j = 0; j < 4; ++j) pack |= ((u32)(int)spikef(cc[j])) << (8 * j);
  *(u32*)&dst[(size_t)i * 4] = pack;
}

// ---------------- i8 GEMM: C(16384 x 1024) = A(i8) x W^T, fused epilogue ----------------
// Tile 256x128 (512 blocks), 8 waves (4 wr x 2 wc), wave tile 64x64, BK=64, NT=16.
// PAIR: B row-stride 2048 (hi|lo), dual i32 acc, val=(256*acch+accl)*alpha/131072+beta
// MODE 0: spike -> i8 natural (B,N,C)      (Q)
// MODE 1: spike -> i8 transposed (B,H,D,N) (K/V)
// MODE 2: f32 natural, no spike            (O -> d_out)
template <int MODE, bool PAIR>
__global__ __launch_bounds__(512) void gemmi8_k(const u8* __restrict__ A,
                                                const char* __restrict__ B,
                                                const float* __restrict__ alpha,
                                                const float* __restrict__ beta,
                                                void* __restrict__ outp) {
  constexpr int NT = 16;
  constexpr int BUFSZ = PAIR ? 32768 : 24576;  // A 16KB + Bhi 8KB (+ Blo 8KB)
  __shared__ u8 lds[2 * BUFSZ];
  const int t = threadIdx.x;
  const int w = t >> 6, ln = t & 63;
  const int wr = w >> 1, wc = w & 1;  // 4 x 2 wave grid
  const int lr = ln & 15, lg = ln >> 4;

  // XCD-grouped: each XCD owns 8 bm-panels x all 8 bn
  const int lid = blockIdx.x;
  const int xcd = lid & 7, idx = lid >> 3;  // idx 0..63
  const int bm = xcd * 8 + (idx >> 3);      // 0..63
  const int bn = idx & 7;                   // 0..7

  const size_t abase = (size_t)(bm * 256) * 1024;
  const int srow = t >> 2;                            // 0..127
  const int sc16 = ((t & 3) ^ ((t >> 3) & 3)) * 16;   // pre-swizzled src chunk
  const int wofs = w * 1024;                          // per-wave LDS dest offset

  auto stA = [&](int tile, int half) {
    g2l16(A + abase + (size_t)(half * 128 + srow) * 1024 + tile * 64 + sc16,
          lds + (tile & 1) * BUFSZ + half * 8192 + wofs);
  };
  auto stBh = [&](int tile) {
    const size_t bb = (size_t)(bn * 128 + srow) * (PAIR ? 2048 : 1024);
    g2l16(B + bb + tile * 64 + sc16, lds + (tile & 1) * BUFSZ + 16384 + wofs);
  };
  auto stBl = [&](int tile) {  // PAIR only
    const size_t bb = (size_t)(bn * 128 + srow) * 2048 + 1024;
    g2l16(B + bb + tile * 64 + sc16, lds + (tile & 1) * BUFSZ + 24576 + wofs);
  };

  // prologue: tile0 full; tile1 minus Blo (PAIR) / complete A-only pattern (single)
  stA(0, 0); stA(0, 1); stBh(0);
  if constexpr (PAIR) stBl(0);
  stA(1, 0); stA(1, 1); stBh(1);

  const int ch = (lg ^ ((lr >> 1) & 3)) * 16;  // swizzled read chunk
  i32x4 acch[4][4] = {};
  i32x4 accl[4][4] = {};  // unused when !PAIR (DCE'd)

  if constexpr (PAIR) {
    asm volatile("s_waitcnt vmcnt(3)" ::: "memory");
  } else {
    asm volatile("s_waitcnt vmcnt(2)" ::: "memory");
  }
  __builtin_amdgcn_s_barrier();

#pragma unroll 1
  for (int tt = 0; tt < NT; ++tt) {
    const u8* Ar = lds + (tt & 1) * BUFSZ + (size_t)wr * 4096;        // wave's 64 A-rows
    const u8* Bh = lds + (tt & 1) * BUFSZ + 16384 + (size_t)wc * 4096;  // wave's 64 B-rows
    const u8* Bl = Bh + 8192;
    i32x4 a[4], bh0[2], bl0[2], bh1[2], bl1[2];

    // ---- P1: read a01 + b01(hi/lo); stage Blo(t+1)|B(t+1); MFMA (mi01 x nj01) ----
#pragma unroll
    for (int mi = 0; mi < 2; ++mi) a[mi] = *(const i32x4*)&Ar[(mi * 16 + lr) * 64 + ch];
#pragma unroll
    for (int nj = 0; nj < 2; ++nj) {
      bh0[nj] = *(const i32x4*)&Bh[(nj * 16 + lr) * 64 + ch];
      if constexpr (PAIR) bl0[nj] = *(const i32x4*)&Bl[(nj * 16 + lr) * 64 + ch];
    }
    if (tt + 1 < NT) { if constexpr (PAIR) stBl(tt + 1); else stBh(tt + 1); }
    __builtin_amdgcn_s_barrier();
    __builtin_amdgcn_s_setprio(1);
#pragma unroll
    for (int mi = 0; mi < 2; ++mi)
#pragma unroll
      for (int nj = 0; nj < 2; ++nj) {
        acch[mi][nj] = mfma8i(a[mi], bh0[nj], acch[mi][nj]);
        if constexpr (PAIR) accl[mi][nj] = mfma8i(a[mi], bl0[nj], accl[mi][nj]);
      }
    __builtin_amdgcn_s_setprio(0);
    __builtin_amdgcn_s_barrier();

    // ---- P2: read a23; MFMA (mi23 x nj01) ----
#pragma unroll
    for (int mi = 0; mi < 2; ++mi)
      a[mi + 2] = *(const i32x4*)&Ar[((mi + 2) * 16 + lr) * 64 + ch];
    __builtin_amdgcn_s_barrier();
    __builtin_amdgcn_s_setprio(1);
#pragma unroll
    for (int mi = 0; mi < 2; ++mi)
#pragma unroll
      for (int nj = 0; nj < 2; ++nj) {
        acch[mi + 2][nj] = mfma8i(a[mi + 2], bh0[nj], acch[mi + 2][nj]);
        if constexpr (PAIR) accl[mi + 2][nj] = mfma8i(a[mi + 2], bl0[nj], accl[mi + 2][nj]);
      }
    __builtin_amdgcn_s_setprio(0);
    __builtin_amdgcn_s_barrier();

    // ---- P3: read b23(hi/lo); stage Ah0,Ah1(t+2); MFMA (mi23 x nj23) ----
#pragma unroll
    for (int nj = 0; nj < 2; ++nj) {
      bh1[nj] = *(const i32x4*)&Bh[((nj + 2) * 16 + lr) * 64 + ch];
      if constexpr (PAIR) bl1[nj] = *(const i32x4*)&Bl[((nj + 2) * 16 + lr) * 64 + ch];
    }
    if (tt + 2 < NT) { stA(tt + 2, 0); stA(tt + 2, 1); }
    __builtin_amdgcn_s_barrier();
    __builtin_amdgcn_s_setprio(1);
#pragma unroll
    for (int mi = 0; mi < 2; ++mi)
#pragma unroll
      for (int nj = 0; nj < 2; ++nj) {
        acch[mi + 2][nj + 2] = mfma8i(a[mi + 2], bh1[nj], acch[mi + 2][nj + 2]);
        if constexpr (PAIR)
          accl[mi + 2][nj + 2] = mfma8i(a[mi + 2], bl1[nj], accl[mi + 2][nj + 2]);
      }
    __builtin_amdgcn_s_setprio(0);
    __builtin_amdgcn_s_barrier();

    // ---- P4: stage Bhi(t+2); MFMA (mi01 x nj23); counted gate ----
    if (tt + 2 < NT) { if constexpr (PAIR) stBh(tt + 2); }
    if constexpr (!PAIR) { if (tt + 2 < NT) stBh(tt + 2); }
    __builtin_amdgcn_s_barrier();
    __builtin_amdgcn_s_setprio(1);
#pragma unroll
    for (int mi = 0; mi < 2; ++mi)
#pragma unroll
      for (int nj = 0; nj < 2; ++nj) {
        acch[mi][nj + 2] = mfma8i(a[mi], bh1[nj], acch[mi][nj + 2]);
        if constexpr (PAIR) accl[mi][nj + 2] = mfma8i(a[mi], bl1[nj], accl[mi][nj + 2]);
      }
    __builtin_amdgcn_s_setprio(0);
    // gate for tile tt+1: younger-than-(its last piece) = stages issued at P3/P4
    if (tt < NT - 2) {
      if constexpr (PAIR) { asm volatile("s_waitcnt vmcnt(3)" ::: "memory"); }
      else               { asm volatile("s_waitcnt vmcnt(3)" ::: "memory"); }
    } else if (tt == NT - 2) {
      asm volatile("s_waitcnt vmcnt(0)" ::: "memory");
    }
    __builtin_amdgcn_s_barrier();
  }

  // ---- epilogue ----
#pragma unroll
  for (int nj = 0; nj < 4; ++nj) {
    const int gn = bn * 128 + wc * 64 + nj * 16 + lr;
    const float al = alpha[gn], be = beta[gn];
    const float s1 = PAIR ? al * (1.f / 512.f) : al * (1.f / 1024.f);
    const float s2 = al * (1.f / 131072.f);
#pragma unroll
    for (int mi = 0; mi < 4; ++mi) {
      const int gm0 = bm * 256 + wr * 64 + mi * 16 + lg * 4;
      float vals[4];
#pragma unroll
      for (int r = 0; r < 4; ++r) {
        float acc = (float)acch[mi][nj][r] * s1;
        if constexpr (PAIR) acc += (float)accl[mi][nj][r] * s2;
        vals[r] = acc + be;
      }
      if constexpr (MODE == 0) {
        u8* o = (u8*)outp;
#pragma unroll
        for (int r = 0; r < 4; ++r)
          o[(size_t)(gm0 + r) * 1024 + gn] = (u8)(int)spikef(vals[r]);
      } else if constexpr (MODE == 1) {
        u8* o = (u8*)outp;
        const int bi = gm0 >> 12, tok = gm0 & 4095;
        const int hh = gn >> 6, dd = gn & 63;
        u32 pack = 0;
#pragma unroll
        for (int r = 0; r < 4; ++r) pack |= ((u32)(int)spikef(vals[r])) << (8 * r);
        *(u32*)&o[((size_t)((bi * 16 + hh) * 64 + dd)) * 4096 + tok] = pack;
      } else {
        float* o = (float*)outp;
#pragma unroll
        for (int r = 0; r < 4; ++r) o[(size_t)(gm0 + r) * 1024 + gn] = vals[r];
      }
    }
  }
}

// ---------------- scores = K^T V (i8, exact), per (b,h) 64x64 ----------------
__global__ __launch_bounds__(256) void scores_k(const u8* __restrict__ Kt,
                                                const u8* __restrict__ Vt,
                                                float* __restrict__ sc) {
  __shared__ u8 lsA[4096], lsB[4096];
  const int t = threadIdx.x;
  const int bh = blockIdx.y, ck = blockIdx.x;
  const int wv = t >> 6, ln = t & 63;
  const int wm = wv & 1, wn = wv >> 1;
  const int lr = ln & 15, lg = ln >> 4;
  const size_t base = (size_t)bh * 262144 + (size_t)ck * 1024;
  i32x4 acc[2][2] = {};
  const int srow = t >> 2;                             // 0..63
  const int schunk = ((t & 3) ^ ((t >> 3) & 3)) * 16;  // bytes
  const int wofs = wv * 1024;
  const int ch = (lg ^ ((lr >> 1) & 3)) * 16;

  for (int kt = 0; kt < 16; ++kt) {
    __syncthreads();
    g2l16(Kt + base + (size_t)srow * 4096 + kt * 64 + schunk, lsA + wofs);
    g2l16(Vt + base + (size_t)srow * 4096 + kt * 64 + schunk, lsB + wofs);
    __syncthreads();
    i32x4 fa[2], fb[2];
#pragma unroll
    for (int mi = 0; mi < 2; ++mi)
      fa[mi] = *(const i32x4*)&lsA[(wm * 32 + mi * 16 + lr) * 64 + ch];
#pragma unroll
    for (int nj = 0; nj < 2; ++nj)
      fb[nj] = *(const i32x4*)&lsB[(wn * 32 + nj * 16 + lr) * 64 + ch];
#pragma unroll
    for (int mi = 0; mi < 2; ++mi)
#pragma unroll
      for (int nj = 0; nj < 2; ++nj) acc[mi][nj] = mfma8i(fa[mi], fb[nj], acc[mi][nj]);
  }
  float* dst = sc + (size_t)bh * 4096;
#pragma unroll
  for (int mi = 0; mi < 2; ++mi)
#pragma unroll
    for (int nj = 0; nj < 2; ++nj)
#pragma unroll
      for (int r = 0; r < 4; ++r) {
        int d = wm * 32 + mi * 16 + lg * 4 + r;
        int e = wn * 32 + nj * 16 + lr;
        atomicAdd(&dst[d * 64 + e], (float)acc[mi][nj][r]);
      }
}

// ---------------- phase B: Xo = spike(0.125 * Q @ scores), full i8 ----------------
// scores split exactly: s = hi*256 + lo, lo in [-128,127]; |s| <= ~2200 -> hi in [-9,9].
__global__ __launch_bounds__(256) void phaseB_k(const u8* __restrict__ Qs,
                                                const float* __restrict__ sc,
                                                u8* __restrict__ Xo) {
  __shared__ u8 lsQ[128 * 64];   // swizzled, staged via g2l16
  __shared__ char sTh[64 * 64];  // [e][d] hi (unswizzled)
  __shared__ char sTl[64 * 64];  // [e][d] lo
  const int t = threadIdx.x;
  const int mc = blockIdx.x, bh = blockIdx.y;
  const int b = bh >> 4, h = bh & 15;
  const int wv = t >> 6, ln = t & 63;
  const int lr = ln & 15, lg = ln >> 4;

  // split scores into exact i8 hi/lo, transposed [e][d]
#pragma unroll
  for (int i = 0; i < 16; ++i) {
    int idx = i * 256 + t;
    int dd = idx >> 6, ee = idx & 63;
    int iv = (int)sc[(size_t)bh * 4096 + idx];
    int lo = ((iv + 128) & 255) - 128;
    int hi = (iv - lo) >> 8;
    sTh[ee * 64 + dd] = (char)hi;
    sTl[ee * 64 + dd] = (char)lo;
  }

  // stage Q chunk (128 tokens x 64 ch) swizzled
  const size_t qbase = ((size_t)(b * 4096 + mc * 128)) * 1024 + h * 64;
  const int srow = t >> 2;                            // 0..63
  const int sc16 = ((t & 3) ^ ((t >> 3) & 3)) * 16;
#pragma unroll
  for (int c = 0; c < 2; ++c)
    g2l16(Qs + qbase + (size_t)(c * 64 + srow) * 1024 + sc16, lsQ + c * 4096 + wv * 1024);
  __syncthreads();

  const int ch = (lg ^ ((lr >> 1) & 3)) * 16;
  i32x4 acch[2][4] = {};
  i32x4 accl[2][4] = {};
  i32x4 qa[2];
#pragma unroll
  for (int mi = 0; mi < 2; ++mi)
    qa[mi] = *(const i32x4*)&lsQ[(wv * 32 + mi * 16 + lr) * 64 + ch];
#pragma unroll
  for (int nj = 0; nj < 4; ++nj) {
    i32x4 fh = *(const i32x4*)&sTh[(nj * 16 + lr) * 64 + lg * 16];
    i32x4 fl = *(const i32x4*)&sTl[(nj * 16 + lr) * 64 + lg * 16];
#pragma unroll
    for (int mi = 0; mi < 2; ++mi) {
      acch[mi][nj] = mfma8i(qa[mi], fh, acch[mi][nj]);
      accl[mi][nj] = mfma8i(qa[mi], fl, accl[mi][nj]);
    }
  }
#pragma unroll
  for (int mi = 0; mi < 2; ++mi)
#pragma unroll
    for (int nj = 0; nj < 4; ++nj)
#pragma unroll
      for (int r = 0; r < 4; ++r) {
        int tok = mc * 128 + wv * 32 + mi * 16 + lg * 4 + r;
        int e = nj * 16 + lr;
        // exact integer dot = 256*acch + accl; SCALE = 0.125
        float pre = 0.125f * (256.f * (float)acch[mi][nj][r] + (float)accl[mi][nj][r]);
        Xo[((size_t)(b * 4096 + tok)) * 1024 + h * 64 + e] = (u8)(int)spikef(pre);
      }
}

// ---------------- host launch ----------------

extern "C" void kernel_launch(void* const* d_in, const int* in_sizes, int n_in,
                              void* d_out, int out_size, void* d_ws, size_t ws_size,
                              hipStream_t stream) {
  (void)in_sizes; (void)n_in; (void)out_size; (void)ws_size;

  const float* xin[3] = {(const float*)d_in[0], (const float*)d_in[1], (const float*)d_in[2]};
  const float* Wf[4] = {(const float*)d_in[3], (const float*)d_in[7],
                        (const float*)d_in[11], (const float*)d_in[15]};
  const float* Bf[4] = {(const float*)d_in[4], (const float*)d_in[8],
                        (const float*)d_in[12], (const float*)d_in[16]};
  const float* Sf[4] = {(const float*)d_in[5], (const float*)d_in[9],
                        (const float*)d_in[13], (const float*)d_in[17]};
  const float* Tf[4] = {(const float*)d_in[6], (const float*)d_in[10],
                        (const float*)d_in[14], (const float*)d_in[18]};

  char* ws = (char*)d_ws;
  const size_t MB = 1ull << 20;
  char* W2k = ws + 0 * MB;                 // 2MB (1024x2048 i8 pair)
  char* W2v = ws + 2 * MB;                 // 2MB
  char* W1q = ws + 4 * MB;                 // 1MB (1024x1024 i8)
  char* W1o = ws + 5 * MB;                 // 1MB
  float* betas = (float*)(ws + 6 * MB);    // 4x1024 f32
  u8* q8 = (u8*)(ws + 8 * MB);             // 16MB (B,N,C) i8
  u8* k8 = (u8*)(ws + 24 * MB);            // 16MB
  u8* v8 = (u8*)(ws + 40 * MB);            // 16MB
  u8* Qs = (u8*)(ws + 56 * MB);            // 16MB (B,N,C) i8 spikes
  u8* Ktp = (u8*)(ws + 72 * MB);           // 16MB (B*H,64,4096) i8
  u8* Vtp = (u8*)(ws + 88 * MB);           // 16MB
  u8* Xo = (u8*)(ws + 104 * MB);           // 16MB (B,N,C) i8

  float* out0 = (float*)d_out;
  float* scores = out0 + 16777216;  // 4*16*64*64 f32

  // prep (weights + betas)
  prep_i8_k<<<1025, 256, 0, stream>>>((const float4*)Wf[0], W1q, Bf[0], Sf[0], Tf[0], betas);
  prep_pair_k<<<1025, 256, 0, stream>>>((const float4*)Wf[1], W2k, Bf[1], Sf[1], Tf[1],
                                        betas + 1024);
  prep_pair_k<<<1025, 256, 0, stream>>>((const float4*)Wf[2], W2v, Bf[2], Sf[2], Tf[2],
                                        betas + 2048);
  prep_i8_k<<<1025, 256, 0, stream>>>((const float4*)Wf[3], W1o, Bf[3], Sf[3], Tf[3],
                                      betas + 3072);

  // quantize all three inputs -> i8
  quant3_k<<<dim3(16384, 3), 256, 0, stream>>>((const float4*)xin[0], (const float4*)xin[1],
                                               (const float4*)xin[2], q8, k8, v8);

  // GEMMs (512 blocks of 512 threads)
  gemmi8_k<0, false><<<512, 512, 0, stream>>>(q8, W1q, Sf[0], betas, Qs);
  gemmi8_k<1, true><<<512, 512, 0, stream>>>(k8, W2k, Sf[1], betas + 1024, Ktp);
  gemmi8_k<1, true><<<512, 512, 0, stream>>>(v8, W2v, Sf[2], betas + 2048, Vtp);

  // scores (exact ints, deterministic)
  hipMemsetAsync(scores, 0, 262144 * sizeof(float), stream);
  scores_k<<<dim3(4, 64), 256, 0, stream>>>(Ktp, Vtp, scores);

  // phase B -> Xo (i8)
  phaseB_k<<<dim3(32, 64), 256, 0, stream>>>(Qs, scores, Xo);

  // final conv_bn -> f32 d_out
  gemmi8_k<2, false><<<512, 512, 0, stream>>>(Xo, W1o, Sf[3], betas + 3072, (void*)out0);
}